// Round 13
// baseline (381.804 us; speedup 1.0000x reference)
//
#include <hip/hip_runtime.h>
#include <hip/hip_bf16.h>

#define N 8192
#define DIN 128
#define DHID 256
#define DOUT 64

typedef __attribute__((ext_vector_type(8))) short short8;
typedef __attribute__((ext_vector_type(8))) unsigned short u16x8;
typedef __attribute__((ext_vector_type(4))) float f32x4;

typedef __attribute__((address_space(1))) const unsigned int GlbU32;
typedef __attribute__((address_space(3))) unsigned int LdsU32;

__device__ inline void gload16(const void* g, void* l) {
  __builtin_amdgcn_global_load_lds((GlbU32*)g, (LdsU32*)l, 16, 0, 0);
}

#define LGKM_BAR()                                            \
  do {                                                        \
    asm volatile("s_waitcnt lgkmcnt(0)" ::: "memory");        \
    __builtin_amdgcn_sched_barrier(0);                        \
    __builtin_amdgcn_s_barrier();                             \
    __builtin_amdgcn_sched_barrier(0);                        \
  } while (0)

#define VM_BAR(nstr)                                          \
  do {                                                        \
    asm volatile("s_waitcnt vmcnt(" nstr ")" ::: "memory");   \
    __builtin_amdgcn_sched_barrier(0);                        \
    __builtin_amdgcn_s_barrier();                             \
    __builtin_amdgcn_sched_barrier(0);                        \
  } while (0)

__device__ inline unsigned short f2bf(float x) {
  unsigned u = __float_as_uint(x);
  u += 0x7FFF + ((u >> 16) & 1);   // RNE
  return (unsigned short)(u >> 16);
}
__device__ inline float bf2f(unsigned short u) {
  return __uint_as_float(((unsigned)u) << 16);
}
__device__ inline float sig_clip(float x) {
  float s = 1.0f / (1.0f + __expf(-x));
  return fmaxf(s, 0.1f);
}

// ---------------- K0: pack (A>0) into interleaved bitmask, 8 MB ----------------
__global__ __launch_bounds__(256) void maskpack(const float* __restrict__ A,
                                                unsigned long long* __restrict__ Mb) {
  size_t i = (size_t)blockIdx.x * 256 + threadIdx.x;
  size_t step = (size_t)gridDim.x * 256;
  int l = threadIdx.x & 63;
  for (; i < (size_t)N * N / 4; i += step) {
    f32x4 a = *(const f32x4*)&A[i * 4];
    unsigned long long b0 = __ballot(a[0] > 0.f);
    unsigned long long b1 = __ballot(a[1] > 0.f);
    unsigned long long b2 = __ballot(a[2] > 0.f);
    unsigned long long b3 = __ballot(a[3] > 0.f);
    size_t g = (i - l) >> 6;
    if (l < 4) {
      unsigned long long bb = (l == 0) ? b0 : (l == 1) ? b1 : (l == 2) ? b2 : b3;
      Mb[g * 4 + l] = bb;
    }
  }
}

// ---------------- K1: BatchNorm statistics ----------------
__global__ void bn_stats(const float* __restrict__ H, const float* __restrict__ bnw,
                         const float* __restrict__ bnb, float* __restrict__ scale,
                         float* __restrict__ shift) {
  int f = blockIdx.x;
  int t = threadIdx.x;
  float s = 0.f, sq = 0.f;
  for (int r = t; r < N; r += 256) {
    float v = H[(size_t)r * DIN + f];
    s += v; sq += v * v;
  }
  __shared__ float ss[256], s2[256];
  ss[t] = s; s2[t] = sq;
  __syncthreads();
  for (int o = 128; o > 0; o >>= 1) {
    if (t < o) { ss[t] += ss[t + o]; s2[t] += s2[t + o]; }
    __syncthreads();
  }
  if (t == 0) {
    float mean = ss[0] * (1.0f / N);
    float var = s2[0] * (1.0f / N) - mean * mean;
    float sc = rsqrtf(var + 1e-5f) * bnw[f];
    scale[f] = sc;
    shift[f] = bnb[f] - mean * sc;
  }
}

// ---------------- K2: Hn -> Hx bf16 [N,256], M2T bf16 [64][N] ----------------
__global__ __launch_bounds__(256) void proj(const float* __restrict__ H,
                     const float* __restrict__ scale, const float* __restrict__ shift,
                     const float* __restrict__ Wt, const float* __restrict__ bt,
                     const float* __restrict__ Wo, const float* __restrict__ bo,
                     unsigned short* __restrict__ Hx, unsigned short* __restrict__ M2T) {
  __shared__ float hn[8][DIN];
  int i0 = blockIdx.x * 8;
  int t = threadIdx.x;
  #pragma unroll
  for (int rep = 0; rep < 4; ++rep) {
    int idx = rep * 256 + t;
    int r = idx >> 7, c = idx & 127;
    float h = H[(size_t)(i0 + r) * DIN + c];
    hn[r][c] = fmaf(h, scale[c], shift[c]);
  }
  __syncthreads();
  {
    int c = t;
    float acc[8];
    float b = bt[c];
    #pragma unroll
    for (int r = 0; r < 8; ++r) acc[r] = b;
    for (int k = 0; k < DIN; ++k) {
      float w = Wt[k * DHID + c];
      #pragma unroll
      for (int r = 0; r < 8; ++r) acc[r] = fmaf(hn[r][k], w, acc[r]);
    }
    #pragma unroll
    for (int r = 0; r < 8; ++r) Hx[(size_t)(i0 + r) * DHID + c] = f2bf(acc[r]);
  }
  if (t < DOUT) {
    int c = t;
    float acc[8];
    float b = bo[c];
    #pragma unroll
    for (int r = 0; r < 8; ++r) acc[r] = b;
    for (int k = 0; k < DIN; ++k) {
      float w = Wo[k * DOUT + c];
      #pragma unroll
      for (int r = 0; r < 8; ++r) acc[r] = fmaf(hn[r][k], w, acc[r]);
    }
    u16x8 v;
    #pragma unroll
    for (int r = 0; r < 8; ++r) v[r] = f2bf(acc[r]);
    *(u16x8*)&M2T[(size_t)c * N + i0] = v;
  }
}

// ---------------- K3/K4: sband — streaming band kernel, counted-vmcnt pipeline ----------------
// Block = 64-row i-tile (A in LDS) x band of LT 64-col j-tiles. B chunks (64x64)
// double-buffered; masks stream via global_load_lds into mstg (no register deps).
// DOPV=0: rowsums only.  DOPV=1: scale -> coalesced Ahat f32 + fused PV -> out.
// LDS u16 offsets: lA [0,16384); LB0 16384; LB1 20480; (DOPV) LVB 24576 [64][72];
// MST = DOPV ? 29184 : 24576 (1024 u16 real, waves 2/3 duplicate into same dst).
template <int DOPV, int LT>
__global__ __launch_bounds__(256, 2) void sband(const unsigned short* __restrict__ Hx,
                     const unsigned long long* __restrict__ Mb,
                     const float* __restrict__ dd,
                     const unsigned short* __restrict__ M2T,
                     float* __restrict__ Ahat, float* __restrict__ out,
                     float* __restrict__ rowsum) {
  __shared__ unsigned short lsh[DOPV ? 30208 : 25600];
  __shared__ unsigned mbt32[64][4];
  const int LB0 = 16384, LB1 = 20480;
  const int LVB = 24576;
  const int MST = DOPV ? 29184 : 24576;
  const int blk = blockIdx.x;
  const int NB = DOPV ? 16 : 8;           // bands per row of tiles
  const int jq = blk & (NB - 1);          // XCD-affine band id
  const int it = blk >> (DOPV ? 4 : 3);   // 0..127
  const int i0 = it * 64;
  const int t = threadIdx.x;
  const int w = t >> 6, l = t & 63;
  const int lr = l & 15, lg = l >> 4;
  const int srow = l >> 3;
  const int scol = ((l & 7) ^ srow) * 8;
  const int fswz = (lr & 7) * 8;
  const int th = t & 127;

  // ---- prologue: A-init (8), mask(t0) (1), chunk(0,c0) (2), di ----
  #pragma unroll
  for (int itr = 0; itr < 8; ++itr) {
    int idx = itr * 4 + w;
    int c4i = idx >> 3, rg = idx & 7;
    int row = rg * 8 + srow;
    gload16(&Hx[(size_t)(i0 + row) * DHID + c4i * 64 + scol], &lsh[idx * 512]);
  }
  {
    int j00 = jq * LT * 64;
    gload16(&Mb[(size_t)(i0 + (th >> 1)) * 128 + (size_t)(j00 >> 8) * 4 + (th & 1) * 2],
            &lsh[MST + (w & 1) * 512]);
    #pragma unroll
    for (int itr = 0; itr < 2; ++itr) {
      int rg = itr * 4 + w;
      int row = rg * 8 + srow;
      gload16(&Hx[(size_t)(j00 + row) * DHID + scol], &lsh[LB0 + rg * 512]);
    }
  }
  float di[4];
  if (DOPV) {
    #pragma unroll
    for (int r = 0; r < 4; ++r) di[r] = dd[i0 + w * 16 + lg * 4 + r];
  }
  VM_BAR("0");

  float rs[4] = {0.f, 0.f, 0.f, 0.f};
  f32x4 acc2[4];
  f32x4 zero = {0.f, 0.f, 0.f, 0.f};
  #pragma unroll
  for (int n = 0; n < 4; ++n) acc2[n] = zero;

  for (int tt = 0; tt < LT; ++tt) {
    const int j0 = (jq * LT + tt) * 64;
    f32x4 acc[4];
    #pragma unroll
    for (int n = 0; n < 4; ++n) acc[n] = zero;

    // ---- K-loop: dbuf chunks, counted vmcnt (never drains stores/prefetch) ----
    #pragma unroll
    for (int c4 = 0; c4 < 4; ++c4) {
      bool isLast = (tt == LT - 1) && (c4 == 3);
      if (!isLast) {
        int njt = (c4 == 3) ? tt + 1 : tt;
        int nc4 = (c4 + 1) & 3;
        int nj0 = (jq * LT + njt) * 64;
        int dstoff = (c4 & 1) ? LB0 : LB1;
        #pragma unroll
        for (int itr = 0; itr < 2; ++itr) {
          int rg = itr * 4 + w;
          int row = rg * 8 + srow;
          gload16(&Hx[(size_t)(nj0 + row) * DHID + nc4 * 64 + scol], &lsh[dstoff + rg * 512]);
        }
      }
      if (c4 == 0)      { if (DOPV) VM_BAR("17"); else VM_BAR("3"); }
      else if (c4 == 3) { if (tt < LT - 1) VM_BAR("2"); else VM_BAR("0"); }
      else              VM_BAR("2");
      const int curoff = (c4 & 1) ? LB1 : LB0;
      #pragma unroll
      for (int kk = 0; kk < 2; ++kk) {
        int c = (kk * 32 + lg * 8) ^ fswz;
        short8 a0 = *(const short8*)&lsh[c4 * 4096 + (w * 16 + lr) * 64 + c];
        short8 bf[4];
        #pragma unroll
        for (int n = 0; n < 4; ++n)
          bf[n] = *(const short8*)&lsh[curoff + (n * 16 + lr) * 64 + c];
        #pragma unroll
        for (int n = 0; n < 4; ++n)
          acc[n] = __builtin_amdgcn_mfma_f32_16x16x32_bf16(a0, bf[n], acc[n], 0, 0, 0);
      }
      LGKM_BAR();   // buf reads retired before reuse; no vmem drain
    }

    // ---- mask conversion: mstg u64 -> 16-bit windows in mbt32 ----
    {
      int crow = t >> 2, ce = t & 3;
      unsigned long long cv = *(const unsigned long long*)&lsh[MST + crow * 16 + ce * 4];
      int sh = (j0 & 192) >> 2;
      mbt32[crow][ce] = (unsigned)((cv >> sh) & 0xFFFFull);
    }
    LGKM_BAR();

    // ---- epilogue ----
    float dj[4];
    if (DOPV) {
      #pragma unroll
      for (int n = 0; n < 4; ++n) dj[n] = dd[j0 + n * 16 + lr];
    }
    #pragma unroll
    for (int r = 0; r < 4; ++r) {
      int rl = w * 16 + lg * 4 + r;
      int gi = i0 + rl;
      unsigned mw = mbt32[rl][lr & 3];
      #pragma unroll
      for (int n = 0; n < 4; ++n) {
        int gj = j0 + n * 16 + lr;
        float ms = ((mw >> (n * 4 + (lr >> 2))) & 1u) ? 1.f : 0.f;
        float v = sig_clip(acc[n][r]) * ms + (gi == gj ? 1.f : 0.f);
        if (DOPV)
          lsh[LVB + rl * 72 + n * 16 + lr] = f2bf(v * di[r] * dj[n]);
        else
          rs[r] += v;
      }
    }
    // next tile's mask stream (oldest of the new queue entries)
    if (tt < LT - 1) {
      int nj0 = (jq * LT + tt + 1) * 64;
      gload16(&Mb[(size_t)(i0 + (th >> 1)) * 128 + (size_t)(nj0 >> 8) * 4 + (th & 1) * 2],
              &lsh[MST + (w & 1) * 512]);
    }

    if (DOPV) {
      LGKM_BAR();   // lVb visible; prefetch/stores keep flying
      // PV first (bfr are newest -> compiler waits don't touch stores)
      #pragma unroll
      for (int kk2 = 0; kk2 < 2; ++kk2) {
        short8 a2 = *(const short8*)&lsh[LVB + (w * 16 + lr) * 72 + kk2 * 32 + lg * 8];
        short8 br[4];
        #pragma unroll
        for (int n = 0; n < 4; ++n)
          br[n] = *(const short8*)&M2T[(size_t)(n * 16 + lr) * N + j0 + kk2 * 32 + lg * 8];
        #pragma unroll
        for (int n = 0; n < 4; ++n)
          acc2[n] = __builtin_amdgcn_mfma_f32_16x16x32_bf16(a2, br[n], acc2[n], 0, 0, 0);
      }
      // coalesced Ahat f32 store pass (128 B contiguous per row), newest in queue
      #pragma unroll
      for (int p = 0; p < 2; ++p) {
        int row = p * 32 + (t >> 3);
        int cc = (t & 7) * 8;
        u16x8 vv = *(const u16x8*)&lsh[LVB + row * 72 + cc];
        f32x4 o0, o1;
        o0[0] = bf2f(vv[0]); o0[1] = bf2f(vv[1]); o0[2] = bf2f(vv[2]); o0[3] = bf2f(vv[3]);
        o1[0] = bf2f(vv[4]); o1[1] = bf2f(vv[5]); o1[2] = bf2f(vv[6]); o1[3] = bf2f(vv[7]);
        size_t idx = (size_t)(i0 + row) * N + j0 + cc;
        *(f32x4*)&Ahat[idx] = o0;
        *(f32x4*)&Ahat[idx + 4] = o1;
      }
    }
  }

  if (DOPV) {
    #pragma unroll
    for (int n = 0; n < 4; ++n)
      #pragma unroll
      for (int r = 0; r < 4; ++r) {
        int gi = i0 + w * 16 + lg * 4 + r;
        atomicAdd(&out[(size_t)gi * DOUT + n * 16 + lr], acc2[n][r]);
      }
  } else {
    #pragma unroll
    for (int r = 0; r < 4; ++r) {
      float p = rs[r];
      p += __shfl_xor(p, 1);
      p += __shfl_xor(p, 2);
      p += __shfl_xor(p, 4);
      p += __shfl_xor(p, 8);
      if (lr == 0) atomicAdd(&rowsum[i0 + w * 16 + lg * 4 + r], p);
    }
  }
}

// ---------------- K3b: d = rsqrt(rowsum), in place ----------------
__global__ void dfin(float* rs) {
  int i = blockIdx.x * 256 + threadIdx.x;
  if (i < N) rs[i] = rsqrtf(rs[i]);
}

// ---------------- K5: LeakyReLU on out ----------------
__global__ void leaky(float* out) {
  int i = blockIdx.x * 256 + threadIdx.x;
  if (i < N * DOUT) {
    float x = out[i];
    out[i] = x >= 0.f ? x : 0.01f * x;
  }
}

extern "C" void kernel_launch(void* const* d_in, const int* in_sizes, int n_in,
                              void* d_out, int out_size, void* d_ws, size_t ws_size,
                              hipStream_t stream) {
  const float* H   = (const float*)d_in[0];
  const float* A   = (const float*)d_in[1];
  const float* bnw = (const float*)d_in[2];
  const float* bnb = (const float*)d_in[3];
  const float* Wt  = (const float*)d_in[4];
  const float* bt  = (const float*)d_in[5];
  const float* Wo  = (const float*)d_in[6];
  const float* bo  = (const float*)d_in[7];
  float* out = (float*)d_out;
  float* Ahat = out + (size_t)N * DOUT;

  char* ws = (char*)d_ws;
  float* scale  = (float*)(ws + 0);
  float* shift  = (float*)(ws + 512);
  float* rowsum = (float*)(ws + 4096);                    // becomes d after dfin
  unsigned short* M2T = (unsigned short*)(ws + 65536);    // 1 MB slot [64][N]
  unsigned short* Hx  = (unsigned short*)(ws + 2097152);  // 4 MB slot
  unsigned long long* Mb = (unsigned long long*)(ws + (size_t)(6u << 20));  // 8 MB bitmask

  hipMemsetAsync(rowsum, 0, N * sizeof(float), stream);
  hipMemsetAsync(out, 0, (size_t)N * DOUT * sizeof(float), stream);

  maskpack<<<4096, 256, 0, stream>>>(A, Mb);
  bn_stats<<<DIN, 256, 0, stream>>>(H, bnw, bnb, scale, shift);
  proj<<<N / 8, 256, 0, stream>>>(H, scale, shift, Wt, bt, Wo, bo, Hx, M2T);
  sband<0, 16><<<1024, 256, 0, stream>>>(Hx, Mb, nullptr, nullptr, nullptr, nullptr, rowsum);
  dfin<<<N / 256, 256, 0, stream>>>(rowsum);
  sband<1, 8><<<2048, 256, 0, stream>>>(Hx, Mb, rowsum, M2T, Ahat, out, nullptr);
  leaky<<<(N * DOUT + 255) / 256, 256, 0, stream>>>(out);
}

// Round 14
// 359.726 us; speedup vs baseline: 1.0614x; 1.0614x over previous
//
#include <hip/hip_runtime.h>
#include <hip/hip_bf16.h>

#define N 8192
#define DIN 128
#define DHID 256
#define DOUT 64
#define VP 136   // V-epilogue LDS row stride (ushorts)

typedef __attribute__((ext_vector_type(8))) short short8;
typedef __attribute__((ext_vector_type(8))) unsigned short u16x8;
typedef __attribute__((ext_vector_type(4))) float f32x4;

typedef __attribute__((address_space(1))) const unsigned int GlbU32;
typedef __attribute__((address_space(3))) unsigned int LdsU32;

__device__ inline void gload16(const void* g, void* l) {
  __builtin_amdgcn_global_load_lds((GlbU32*)g, (LdsU32*)l, 16, 0, 0);
}

__device__ inline unsigned short f2bf(float x) {
  unsigned u = __float_as_uint(x);
  u += 0x7FFF + ((u >> 16) & 1);   // RNE
  return (unsigned short)(u >> 16);
}
__device__ inline float bf2f(unsigned short u) {
  return __uint_as_float(((unsigned)u) << 16);
}
__device__ inline float sig_clip(float x) {
  float s = 1.0f / (1.0f + __expf(-x));
  return fmaxf(s, 0.1f);
}

// ---------------- K0: pack (A>0) into interleaved bitmask, 8 MB ----------------
__global__ __launch_bounds__(256) void maskpack(const float* __restrict__ A,
                                                unsigned long long* __restrict__ Mb) {
  size_t i = (size_t)blockIdx.x * 256 + threadIdx.x;
  size_t step = (size_t)gridDim.x * 256;
  int l = threadIdx.x & 63;
  for (; i < (size_t)N * N / 4; i += step) {
    f32x4 a = *(const f32x4*)&A[i * 4];
    unsigned long long b0 = __ballot(a[0] > 0.f);
    unsigned long long b1 = __ballot(a[1] > 0.f);
    unsigned long long b2 = __ballot(a[2] > 0.f);
    unsigned long long b3 = __ballot(a[3] > 0.f);
    size_t g = (i - l) >> 6;
    if (l < 4) {
      unsigned long long bb = (l == 0) ? b0 : (l == 1) ? b1 : (l == 2) ? b2 : b3;
      Mb[g * 4 + l] = bb;
    }
  }
}

// ---------------- K1: BatchNorm statistics ----------------
__global__ void bn_stats(const float* __restrict__ H, const float* __restrict__ bnw,
                         const float* __restrict__ bnb, float* __restrict__ scale,
                         float* __restrict__ shift) {
  int f = blockIdx.x;
  int t = threadIdx.x;
  float s = 0.f, sq = 0.f;
  for (int r = t; r < N; r += 256) {
    float v = H[(size_t)r * DIN + f];
    s += v; sq += v * v;
  }
  __shared__ float ss[256], s2[256];
  ss[t] = s; s2[t] = sq;
  __syncthreads();
  for (int o = 128; o > 0; o >>= 1) {
    if (t < o) { ss[t] += ss[t + o]; s2[t] += s2[t + o]; }
    __syncthreads();
  }
  if (t == 0) {
    float mean = ss[0] * (1.0f / N);
    float var = s2[0] * (1.0f / N) - mean * mean;
    float sc = rsqrtf(var + 1e-5f) * bnw[f];
    scale[f] = sc;
    shift[f] = bnb[f] - mean * sc;
  }
}

// ---------------- K2: Hn -> Hx bf16 [N,256], M2T bf16 [64][N] ----------------
__global__ __launch_bounds__(256) void proj(const float* __restrict__ H,
                     const float* __restrict__ scale, const float* __restrict__ shift,
                     const float* __restrict__ Wt, const float* __restrict__ bt,
                     const float* __restrict__ Wo, const float* __restrict__ bo,
                     unsigned short* __restrict__ Hx, unsigned short* __restrict__ M2T) {
  __shared__ float hn[8][DIN];
  int i0 = blockIdx.x * 8;
  int t = threadIdx.x;
  #pragma unroll
  for (int rep = 0; rep < 4; ++rep) {
    int idx = rep * 256 + t;
    int r = idx >> 7, c = idx & 127;
    float h = H[(size_t)(i0 + r) * DIN + c];
    hn[r][c] = fmaf(h, scale[c], shift[c]);
  }
  __syncthreads();
  {
    int c = t;
    float acc[8];
    float b = bt[c];
    #pragma unroll
    for (int r = 0; r < 8; ++r) acc[r] = b;
    for (int k = 0; k < DIN; ++k) {
      float w = Wt[k * DHID + c];
      #pragma unroll
      for (int r = 0; r < 8; ++r) acc[r] = fmaf(hn[r][k], w, acc[r]);
    }
    #pragma unroll
    for (int r = 0; r < 8; ++r) Hx[(size_t)(i0 + r) * DHID + c] = f2bf(acc[r]);
  }
  if (t < DOUT) {
    int c = t;
    float acc[8];
    float b = bo[c];
    #pragma unroll
    for (int r = 0; r < 8; ++r) acc[r] = b;
    for (int k = 0; k < DIN; ++k) {
      float w = Wo[k * DOUT + c];
      #pragma unroll
      for (int r = 0; r < 8; ++r) acc[r] = fmaf(hn[r][k], w, acc[r]);
    }
    u16x8 v;
    #pragma unroll
    for (int r = 0; r < 8; ++r) v[r] = f2bf(acc[r]);
    *(u16x8*)&M2T[(size_t)c * N + i0] = v;
  }
}

// ---------------- K3: smat — R7-validated symmetric single pass ----------------
// v = clip(sig(Hx Hx^T))*mask + I, it<=jt only; off-diag emits (i,j) and (j,i)
// tiles (different masks), row sums for i-rows + column sums for j-rows.
__global__ __launch_bounds__(256) void smat(const unsigned short* __restrict__ Hx,
                     const unsigned long long* __restrict__ Mb,
                     float* __restrict__ rowsum,
                     unsigned short* __restrict__ Vout) {
  int jt = blockIdx.x, it = blockIdx.y;
  if (jt < it) return;
  __shared__ unsigned short lsh[17408];       // staging la/lb; later the V tile [128][VP]
  __shared__ unsigned mbt32[128][4];
  __shared__ unsigned mbtT[128][4];
  __shared__ float scs[4][128];
  unsigned short* la = lsh;
  unsigned short* lb = lsh + 8192;
  int i0 = it * 128, j0 = jt * 128;
  int t = threadIdx.x;
  int w = t >> 6, l = t & 63;
  int lr = l & 15, lg = l >> 4;
  const bool offdiag = (it != jt);

  if (t < 128) {
    const unsigned long long* src = &Mb[(size_t)(i0 + t) * (N / 64) + (j0 >> 8) * 4];
    int sh = (j0 & 128) ? 32 : 0;
    #pragma unroll
    for (int e = 0; e < 4; ++e)
      mbt32[t][e] = (unsigned)(src[e] >> sh);
  }
  if (offdiag && t < 128) {
    const unsigned long long* srcT = &Mb[(size_t)(j0 + t) * (N / 64) + (i0 >> 8) * 4];
    int shT = (i0 & 128) ? 32 : 0;
    #pragma unroll
    for (int e = 0; e < 4; ++e)
      mbtT[t][e] = (unsigned)(srcT[e] >> shT);
  }

  f32x4 acc[2][8];
  f32x4 zero = {0.f, 0.f, 0.f, 0.f};
  #pragma unroll
  for (int m = 0; m < 2; ++m)
    #pragma unroll
    for (int n = 0; n < 8; ++n) acc[m][n] = zero;

  const int srow = l >> 3;
  const int scol = ((l & 7) ^ srow) * 8;
  const int fswz = (lr & 7) * 8;

  for (int c4 = 0; c4 < 4; ++c4) {
    int k0 = c4 * 64;
    __syncthreads();
    #pragma unroll
    for (int rp = 0; rp < 4; ++rp) {
      int chunk = rp * 4 + w;
      int row = chunk * 8 + srow;
      gload16(&Hx[(size_t)(i0 + row) * DHID + k0 + scol], &la[chunk * 512]);
      gload16(&Hx[(size_t)(j0 + row) * DHID + k0 + scol], &lb[chunk * 512]);
    }
    __syncthreads();
    #pragma unroll
    for (int kk = 0; kk < 2; ++kk) {
      int c = (kk * 32 + lg * 8) ^ fswz;
      short8 af[2], bf[8];
      #pragma unroll
      for (int m = 0; m < 2; ++m)
        af[m] = *(const short8*)&la[(w * 32 + m * 16 + lr) * 64 + c];
      #pragma unroll
      for (int n = 0; n < 8; ++n)
        bf[n] = *(const short8*)&lb[(n * 16 + lr) * 64 + c];
      #pragma unroll
      for (int m = 0; m < 2; ++m)
        #pragma unroll
        for (int n = 0; n < 8; ++n)
          acc[m][n] = __builtin_amdgcn_mfma_f32_16x16x32_bf16(af[m], bf[n], acc[m][n], 0, 0, 0);
    }
  }

  __syncthreads();  // staging fully consumed; lsh becomes the V tile

  // ---- upper tile: v_up = sig*m_up (+I on diag), row sums ----
  #pragma unroll
  for (int m = 0; m < 2; ++m) {
    #pragma unroll
    for (int r = 0; r < 4; ++r) {
      int rl = w * 32 + m * 16 + lg * 4 + r;
      int gi = i0 + rl;
      unsigned mw = mbt32[rl][lr & 3];
      float part = 0.f;
      #pragma unroll
      for (int n = 0; n < 8; ++n) {
        int gj = j0 + n * 16 + lr;
        float ms = ((mw >> (n * 4 + (lr >> 2))) & 1u) ? 1.f : 0.f;
        float v = sig_clip(acc[m][n][r]) * ms + (gi == gj ? 1.f : 0.f);
        part += v;
        lsh[rl * VP + n * 16 + lr] = f2bf(v);
      }
      part += __shfl_xor(part, 1);
      part += __shfl_xor(part, 2);
      part += __shfl_xor(part, 4);
      part += __shfl_xor(part, 8);
      if (lr == 0) atomicAdd(&rowsum[gi], part);
    }
  }

  __syncthreads();
  #pragma unroll
  for (int pass = 0; pass < 8; ++pass) {
    int row = pass * 16 + (t >> 4);
    int cc = (t & 15) * 8;
    u16x8 vv = *(const u16x8*)&lsh[row * VP + cc];
    *(u16x8*)&Vout[(size_t)(i0 + row) * N + j0 + cc] = vv;
  }

  // ---- lower (transposed) tile: v_lo = sig*m_lo, column sums -> rowsum[j-rows] ----
  if (offdiag) {
    __syncthreads();   // upper store pass done reading lsh
    float p[8];
    #pragma unroll
    for (int n = 0; n < 8; ++n) p[n] = 0.f;
    #pragma unroll
    for (int m = 0; m < 2; ++m) {
      #pragma unroll
      for (int r = 0; r < 4; ++r) {
        int rl = w * 32 + m * 16 + lg * 4 + r;
        int bitp = w * 8 + m * 4 + lg;
        #pragma unroll
        for (int n = 0; n < 8; ++n) {
          int c = n * 16 + lr;                       // j-row within tile
          float ms = ((mbtT[c][r] >> bitp) & 1u) ? 1.f : 0.f;
          float v = sig_clip(acc[m][n][r]) * ms;
          p[n] += v;
          lsh[c * VP + rl] = f2bf(v);                // transposed position
        }
      }
    }
    #pragma unroll
    for (int n = 0; n < 8; ++n) {
      p[n] += __shfl_xor(p[n], 16);
      p[n] += __shfl_xor(p[n], 32);
    }
    if (lg == 0) {
      #pragma unroll
      for (int n = 0; n < 8; ++n) scs[w][n * 16 + lr] = p[n];
    }
    __syncthreads();
    if (t < 128) {
      float cs = scs[0][t] + scs[1][t] + scs[2][t] + scs[3][t];
      atomicAdd(&rowsum[j0 + t], cs);
    }
    #pragma unroll
    for (int pass = 0; pass < 8; ++pass) {
      int row = pass * 16 + (t >> 4);
      int cc = (t & 15) * 8;
      u16x8 vv = *(const u16x8*)&lsh[row * VP + cc];
      *(u16x8*)&Vout[(size_t)(j0 + row) * N + i0 + cc] = vv;
    }
  }
}

// ---------------- K3b: d = rsqrt(rowsum), in place ----------------
__global__ void dfin(float* rs) {
  int i = blockIdx.x * 256 + threadIdx.x;
  if (i < N) rs[i] = rsqrtf(rs[i]);
}

// ---------------- K3c: M2T *= d_j in place (bf16) ----------------
__global__ __launch_bounds__(256) void m2scale(unsigned short* __restrict__ M2T,
                                               const float* __restrict__ dd) {
  int idx = blockIdx.x * 256 + threadIdx.x;   // 65536 total
  int c = idx >> 10;
  int j8 = (idx & 1023) * 8;
  u16x8 v = *(u16x8*)&M2T[(size_t)c * N + j8];
  f32x4 d0 = *(const f32x4*)&dd[j8];
  f32x4 d1 = *(const f32x4*)&dd[j8 + 4];
  u16x8 o;
  o[0] = f2bf(bf2f(v[0]) * d0[0]); o[1] = f2bf(bf2f(v[1]) * d0[1]);
  o[2] = f2bf(bf2f(v[2]) * d0[2]); o[3] = f2bf(bf2f(v[3]) * d0[3]);
  o[4] = f2bf(bf2f(v[4]) * d1[0]); o[5] = f2bf(bf2f(v[5]) * d1[1]);
  o[6] = f2bf(bf2f(v[6]) * d1[2]); o[7] = f2bf(bf2f(v[7]) * d1[3]);
  *(u16x8*)&M2T[(size_t)c * N + j8] = o;
}

// ---------------- K4a: pvmm — out = d_i * (V @ M2Ts) ----------------
// V bf16 staged via gload16 (same swizzle as smat); B-frags from prescaled M2Ts (L2).
__global__ __launch_bounds__(256) void pvmm(const unsigned short* __restrict__ V,
                     const float* __restrict__ dd,
                     const unsigned short* __restrict__ M2Ts,
                     float* __restrict__ out) {
  __shared__ unsigned short lv[8192];  // [128][64] linear
  int kc = blockIdx.x;   // 0..15 (j-chunk of 512)
  int it = blockIdx.y;   // 0..63
  int i0 = it * 128;
  int t = threadIdx.x;
  int w = t >> 6, l = t & 63;
  int lr = l & 15, lg = l >> 4;
  const int srow = l >> 3;
  const int scol = ((l & 7) ^ srow) * 8;
  const int fswz = (lr & 7) * 8;

  f32x4 acc[2][4];
  f32x4 zero = {0.f, 0.f, 0.f, 0.f};
  #pragma unroll
  for (int m = 0; m < 2; ++m)
    #pragma unroll
    for (int n = 0; n < 4; ++n) acc[m][n] = zero;

  for (int s = 0; s < 8; ++s) {
    int j0 = kc * 512 + s * 64;
    __syncthreads();
    #pragma unroll
    for (int rp = 0; rp < 4; ++rp) {
      int chunk = rp * 4 + w;
      int row = chunk * 8 + srow;
      gload16(&V[(size_t)(i0 + row) * N + j0 + scol], &lv[chunk * 512]);
    }
    __syncthreads();
    #pragma unroll
    for (int kk = 0; kk < 2; ++kk) {
      int c = (kk * 32 + lg * 8) ^ fswz;
      short8 af[2], bfr[4];
      #pragma unroll
      for (int m = 0; m < 2; ++m)
        af[m] = *(const short8*)&lv[(w * 32 + m * 16 + lr) * 64 + c];
      #pragma unroll
      for (int n = 0; n < 4; ++n)
        bfr[n] = *(const short8*)&M2Ts[(size_t)(n * 16 + lr) * N + j0 + kk * 32 + lg * 8];
      #pragma unroll
      for (int m = 0; m < 2; ++m)
        #pragma unroll
        for (int n = 0; n < 4; ++n)
          acc[m][n] = __builtin_amdgcn_mfma_f32_16x16x32_bf16(af[m], bfr[n], acc[m][n], 0, 0, 0);
    }
  }

  #pragma unroll
  for (int m = 0; m < 2; ++m)
    #pragma unroll
    for (int r = 0; r < 4; ++r) {
      int gi = i0 + w * 32 + m * 16 + lg * 4 + r;
      float di = dd[gi];
      #pragma unroll
      for (int n = 0; n < 4; ++n)
        atomicAdd(&out[(size_t)gi * DOUT + n * 16 + lr], di * acc[m][n][r]);
    }
}

// ---------------- K4b: ascale — pure stream: Ahat = bf2f(v)*di*dj ----------------
__global__ __launch_bounds__(256) void ascale(const unsigned short* __restrict__ V,
                                              const float* __restrict__ dd,
                                              float* __restrict__ Ahat) {
  int row = blockIdx.x;
  float di = dd[row];
  const unsigned short* vr = V + (size_t)row * N;
  float* ar = Ahat + (size_t)row * N;
  #pragma unroll
  for (int itr = 0; itr < 4; ++itr) {
    int c0 = (itr * 256 + threadIdx.x) * 8;
    u16x8 v = *(const u16x8*)&vr[c0];
    f32x4 dj0 = *(const f32x4*)&dd[c0];
    f32x4 dj1 = *(const f32x4*)&dd[c0 + 4];
    f32x4 o0, o1;
    o0[0] = bf2f(v[0]) * di * dj0[0]; o0[1] = bf2f(v[1]) * di * dj0[1];
    o0[2] = bf2f(v[2]) * di * dj0[2]; o0[3] = bf2f(v[3]) * di * dj0[3];
    o1[0] = bf2f(v[4]) * di * dj1[0]; o1[1] = bf2f(v[5]) * di * dj1[1];
    o1[2] = bf2f(v[6]) * di * dj1[2]; o1[3] = bf2f(v[7]) * di * dj1[3];
    *(f32x4*)&ar[c0] = o0;
    *(f32x4*)&ar[c0 + 4] = o1;
  }
}

// ---------------- K5: LeakyReLU on out ----------------
__global__ void leaky(float* out) {
  int i = blockIdx.x * 256 + threadIdx.x;
  if (i < N * DOUT) {
    float x = out[i];
    out[i] = x >= 0.f ? x : 0.01f * x;
  }
}

extern "C" void kernel_launch(void* const* d_in, const int* in_sizes, int n_in,
                              void* d_out, int out_size, void* d_ws, size_t ws_size,
                              hipStream_t stream) {
  const float* H   = (const float*)d_in[0];
  const float* A   = (const float*)d_in[1];
  const float* bnw = (const float*)d_in[2];
  const float* bnb = (const float*)d_in[3];
  const float* Wt  = (const float*)d_in[4];
  const float* bt  = (const float*)d_in[5];
  const float* Wo  = (const float*)d_in[6];
  const float* bo  = (const float*)d_in[7];
  float* out = (float*)d_out;
  float* Ahat = out + (size_t)N * DOUT;

  char* ws = (char*)d_ws;
  float* scale  = (float*)(ws + 0);
  float* shift  = (float*)(ws + 512);
  float* rowsum = (float*)(ws + 4096);                    // becomes d after dfin
  unsigned short* M2T = (unsigned short*)(ws + 65536);    // 1 MB slot [64][N]
  unsigned short* Hx  = (unsigned short*)(ws + 2097152);  // 4 MB slot
  unsigned long long* Mb = (unsigned long long*)(ws + (size_t)(6u << 20));  // 8 MB bitmask
  unsigned short* Vbf = (unsigned short*)(ws + (size_t)(14u << 20));        // 128 MiB slot

  hipMemsetAsync(rowsum, 0, N * sizeof(float), stream);
  hipMemsetAsync(out, 0, (size_t)N * DOUT * sizeof(float), stream);

  maskpack<<<4096, 256, 0, stream>>>(A, Mb);
  bn_stats<<<DIN, 256, 0, stream>>>(H, bnw, bnb, scale, shift);
  proj<<<N / 8, 256, 0, stream>>>(H, scale, shift, Wt, bt, Wo, bo, Hx, M2T);
  smat<<<dim3(64, 64), 256, 0, stream>>>(Hx, Mb, rowsum, Vbf);
  dfin<<<N / 256, 256, 0, stream>>>(rowsum);
  m2scale<<<256, 256, 0, stream>>>(M2T, rowsum);
  pvmm<<<dim3(16, 64), 256, 0, stream>>>(Vbf, rowsum, M2T, out);
  ascale<<<N, 256, 0, stream>>>(Vbf, rowsum, Ahat);
  leaky<<<(N * DOUT + 255) / 256, 256, 0, stream>>>(out);
}

// Round 15
// 317.965 us; speedup vs baseline: 1.2008x; 1.1313x over previous
//
#include <hip/hip_runtime.h>
#include <hip/hip_bf16.h>

#define N 8192
#define DIN 128
#define DHID 256
#define DOUT 64
#define LDP 72   // outmm staging LDS row stride (ushorts)
#define VP 136   // V-epilogue LDS row stride (ushorts)

typedef __attribute__((ext_vector_type(8))) short short8;
typedef __attribute__((ext_vector_type(8))) unsigned short u16x8;
typedef __attribute__((ext_vector_type(4))) float f32x4;

typedef __attribute__((address_space(1))) const unsigned int GlbU32;
typedef __attribute__((address_space(3))) unsigned int LdsU32;

__device__ inline void gload16(const void* g, void* l) {
  __builtin_amdgcn_global_load_lds((GlbU32*)g, (LdsU32*)l, 16, 0, 0);
}

// lgkmcnt-only barrier: LDS ordering without draining vmcnt (global stores keep flying)
#define LGKM_BAR()                                            \
  do {                                                        \
    asm volatile("s_waitcnt lgkmcnt(0)" ::: "memory");        \
    __builtin_amdgcn_sched_barrier(0);                        \
    __builtin_amdgcn_s_barrier();                             \
    __builtin_amdgcn_sched_barrier(0);                        \
  } while (0)

__device__ inline unsigned short f2bf(float x) {
  unsigned u = __float_as_uint(x);
  u += 0x7FFF + ((u >> 16) & 1);   // RNE
  return (unsigned short)(u >> 16);
}
__device__ inline float bf2f(unsigned short u) {
  return __uint_as_float(((unsigned)u) << 16);
}
__device__ inline float sig_clip(float x) {
  float s = 1.0f / (1.0f + __expf(-x));
  return fmaxf(s, 0.1f);
}

// ---------------- K0: pack (A>0) into interleaved bitmask, 8 MB ----------------
__global__ __launch_bounds__(256) void maskpack(const float* __restrict__ A,
                                                unsigned long long* __restrict__ Mb) {
  size_t i = (size_t)blockIdx.x * 256 + threadIdx.x;
  size_t step = (size_t)gridDim.x * 256;
  int l = threadIdx.x & 63;
  for (; i < (size_t)N * N / 4; i += step) {
    f32x4 a = *(const f32x4*)&A[i * 4];
    unsigned long long b0 = __ballot(a[0] > 0.f);
    unsigned long long b1 = __ballot(a[1] > 0.f);
    unsigned long long b2 = __ballot(a[2] > 0.f);
    unsigned long long b3 = __ballot(a[3] > 0.f);
    size_t g = (i - l) >> 6;
    if (l < 4) {
      unsigned long long bb = (l == 0) ? b0 : (l == 1) ? b1 : (l == 2) ? b2 : b3;
      Mb[g * 4 + l] = bb;
    }
  }
}

// ---------------- K1: BatchNorm statistics ----------------
__global__ void bn_stats(const float* __restrict__ H, const float* __restrict__ bnw,
                         const float* __restrict__ bnb, float* __restrict__ scale,
                         float* __restrict__ shift) {
  int f = blockIdx.x;
  int t = threadIdx.x;
  float s = 0.f, sq = 0.f;
  for (int r = t; r < N; r += 256) {
    float v = H[(size_t)r * DIN + f];
    s += v; sq += v * v;
  }
  __shared__ float ss[256], s2[256];
  ss[t] = s; s2[t] = sq;
  __syncthreads();
  for (int o = 128; o > 0; o >>= 1) {
    if (t < o) { ss[t] += ss[t + o]; s2[t] += s2[t + o]; }
    __syncthreads();
  }
  if (t == 0) {
    float mean = ss[0] * (1.0f / N);
    float var = s2[0] * (1.0f / N) - mean * mean;
    float sc = rsqrtf(var + 1e-5f) * bnw[f];
    scale[f] = sc;
    shift[f] = bnb[f] - mean * sc;
  }
}

// ---------------- K2: Hn -> Hx bf16 [N,256], M2T bf16 [64][N] ----------------
__global__ __launch_bounds__(256) void proj(const float* __restrict__ H,
                     const float* __restrict__ scale, const float* __restrict__ shift,
                     const float* __restrict__ Wt, const float* __restrict__ bt,
                     const float* __restrict__ Wo, const float* __restrict__ bo,
                     unsigned short* __restrict__ Hx, unsigned short* __restrict__ M2T) {
  __shared__ float hn[8][DIN];
  int i0 = blockIdx.x * 8;
  int t = threadIdx.x;
  #pragma unroll
  for (int rep = 0; rep < 4; ++rep) {
    int idx = rep * 256 + t;
    int r = idx >> 7, c = idx & 127;
    float h = H[(size_t)(i0 + r) * DIN + c];
    hn[r][c] = fmaf(h, scale[c], shift[c]);
  }
  __syncthreads();
  {
    int c = t;
    float acc[8];
    float b = bt[c];
    #pragma unroll
    for (int r = 0; r < 8; ++r) acc[r] = b;
    for (int k = 0; k < DIN; ++k) {
      float w = Wt[k * DHID + c];
      #pragma unroll
      for (int r = 0; r < 8; ++r) acc[r] = fmaf(hn[r][k], w, acc[r]);
    }
    #pragma unroll
    for (int r = 0; r < 8; ++r) Hx[(size_t)(i0 + r) * DHID + c] = f2bf(acc[r]);
  }
  if (t < DOUT) {
    int c = t;
    float acc[8];
    float b = bo[c];
    #pragma unroll
    for (int r = 0; r < 8; ++r) acc[r] = b;
    for (int k = 0; k < DIN; ++k) {
      float w = Wo[k * DOUT + c];
      #pragma unroll
      for (int r = 0; r < 8; ++r) acc[r] = fmaf(hn[r][k], w, acc[r]);
    }
    u16x8 v;
    #pragma unroll
    for (int r = 0; r < 8; ++r) v[r] = f2bf(acc[r]);
    *(u16x8*)&M2T[(size_t)c * N + i0] = v;
  }
}

// ---------------- K3: smat — symmetric single pass (R7) + exp-once + lgkm barriers ----------------
// v = clip(sig(Hx Hx^T))*mask + I, it<=jt only; off-diag emits (i,j) and (j,i)
// tiles (different masks), row sums for i-rows + column sums for j-rows.
// sig_clip computed ONCE per acc element (cached in acc); epilogue barriers are
// lgkm-only so V global-stores never drain mid-kernel.
__global__ __launch_bounds__(256) void smat(const unsigned short* __restrict__ Hx,
                     const unsigned long long* __restrict__ Mb,
                     float* __restrict__ rowsum,
                     unsigned short* __restrict__ Vout) {
  int jt = blockIdx.x, it = blockIdx.y;
  if (jt < it) return;
  __shared__ unsigned short lsh[17408];       // staging la/lb; later the V tile [128][VP]
  __shared__ unsigned mbt32[128][4];
  __shared__ unsigned mbtT[128][4];
  __shared__ float scs[4][128];
  unsigned short* la = lsh;
  unsigned short* lb = lsh + 8192;
  int i0 = it * 128, j0 = jt * 128;
  int t = threadIdx.x;
  int w = t >> 6, l = t & 63;
  int lr = l & 15, lg = l >> 4;
  const bool offdiag = (it != jt);

  if (t < 128) {
    const unsigned long long* src = &Mb[(size_t)(i0 + t) * (N / 64) + (j0 >> 8) * 4];
    int sh = (j0 & 128) ? 32 : 0;
    #pragma unroll
    for (int e = 0; e < 4; ++e)
      mbt32[t][e] = (unsigned)(src[e] >> sh);
  }
  if (offdiag && t < 128) {
    const unsigned long long* srcT = &Mb[(size_t)(j0 + t) * (N / 64) + (i0 >> 8) * 4];
    int shT = (i0 & 128) ? 32 : 0;
    #pragma unroll
    for (int e = 0; e < 4; ++e)
      mbtT[t][e] = (unsigned)(srcT[e] >> shT);
  }

  f32x4 acc[2][8];
  f32x4 zero = {0.f, 0.f, 0.f, 0.f};
  #pragma unroll
  for (int m = 0; m < 2; ++m)
    #pragma unroll
    for (int n = 0; n < 8; ++n) acc[m][n] = zero;

  const int srow = l >> 3;
  const int scol = ((l & 7) ^ srow) * 8;
  const int fswz = (lr & 7) * 8;

  for (int c4 = 0; c4 < 4; ++c4) {
    int k0 = c4 * 64;
    __syncthreads();
    #pragma unroll
    for (int rp = 0; rp < 4; ++rp) {
      int chunk = rp * 4 + w;
      int row = chunk * 8 + srow;
      gload16(&Hx[(size_t)(i0 + row) * DHID + k0 + scol], &la[chunk * 512]);
      gload16(&Hx[(size_t)(j0 + row) * DHID + k0 + scol], &lb[chunk * 512]);
    }
    __syncthreads();
    #pragma unroll
    for (int kk = 0; kk < 2; ++kk) {
      int c = (kk * 32 + lg * 8) ^ fswz;
      short8 af[2], bf[8];
      #pragma unroll
      for (int m = 0; m < 2; ++m)
        af[m] = *(const short8*)&la[(w * 32 + m * 16 + lr) * 64 + c];
      #pragma unroll
      for (int n = 0; n < 8; ++n)
        bf[n] = *(const short8*)&lb[(n * 16 + lr) * 64 + c];
      #pragma unroll
      for (int m = 0; m < 2; ++m)
        #pragma unroll
        for (int n = 0; n < 8; ++n)
          acc[m][n] = __builtin_amdgcn_mfma_f32_16x16x32_bf16(af[m], bf[n], acc[m][n], 0, 0, 0);
    }
  }

  LGKM_BAR();  // all waves' MFMA ds_reads retired; lsh becomes the V tile

  // ---- upper tile: s = sig_clip(acc) cached in acc; v_up = s*m_up (+I), row sums ----
  #pragma unroll
  for (int m = 0; m < 2; ++m) {
    #pragma unroll
    for (int r = 0; r < 4; ++r) {
      int rl = w * 32 + m * 16 + lg * 4 + r;
      int gi = i0 + rl;
      unsigned mw = mbt32[rl][lr & 3];
      float part = 0.f;
      #pragma unroll
      for (int n = 0; n < 8; ++n) {
        int gj = j0 + n * 16 + lr;
        float s = sig_clip(acc[m][n][r]);
        acc[m][n][r] = s;                       // cache for lower pass (no 2nd exp)
        float ms = ((mw >> (n * 4 + (lr >> 2))) & 1u) ? 1.f : 0.f;
        float v = s * ms + (gi == gj ? 1.f : 0.f);
        part += v;
        lsh[rl * VP + n * 16 + lr] = f2bf(v);
      }
      part += __shfl_xor(part, 1);
      part += __shfl_xor(part, 2);
      part += __shfl_xor(part, 4);
      part += __shfl_xor(part, 8);
      if (lr == 0) atomicAdd(&rowsum[gi], part);
    }
  }

  LGKM_BAR();     // V tile visible; no vmem drain
  #pragma unroll
  for (int pass = 0; pass < 8; ++pass) {
    int row = pass * 16 + (t >> 4);
    int cc = (t & 15) * 8;
    u16x8 vv = *(const u16x8*)&lsh[row * VP + cc];
    *(u16x8*)&Vout[(size_t)(i0 + row) * N + j0 + cc] = vv;
  }

  // ---- lower (transposed) tile: v_lo = s*m_lo, column sums -> rowsum[j-rows] ----
  if (offdiag) {
    LGKM_BAR();   // upper store pass's LDS reads retired; stores keep flying
    float p[8];
    #pragma unroll
    for (int n = 0; n < 8; ++n) p[n] = 0.f;
    #pragma unroll
    for (int m = 0; m < 2; ++m) {
      #pragma unroll
      for (int r = 0; r < 4; ++r) {
        int rl = w * 32 + m * 16 + lg * 4 + r;
        int bitp = w * 8 + m * 4 + lg;
        #pragma unroll
        for (int n = 0; n < 8; ++n) {
          int c = n * 16 + lr;                       // j-row within tile
          float ms = ((mbtT[c][r] >> bitp) & 1u) ? 1.f : 0.f;
          float v = acc[m][n][r] * ms;               // s already cached — no exp
          p[n] += v;
          lsh[c * VP + rl] = f2bf(v);                // transposed position
        }
      }
    }
    #pragma unroll
    for (int n = 0; n < 8; ++n) {
      p[n] += __shfl_xor(p[n], 16);
      p[n] += __shfl_xor(p[n], 32);
    }
    if (lg == 0) {
      #pragma unroll
      for (int n = 0; n < 8; ++n) scs[w][n * 16 + lr] = p[n];
    }
    LGKM_BAR();   // lsh transposed tile + scs visible
    if (t < 128) {
      float cs = scs[0][t] + scs[1][t] + scs[2][t] + scs[3][t];
      atomicAdd(&rowsum[j0 + t], cs);
    }
    #pragma unroll
    for (int pass = 0; pass < 8; ++pass) {
      int row = pass * 16 + (t >> 4);
      int cc = (t & 15) * 8;
      u16x8 vv = *(const u16x8*)&lsh[row * VP + cc];
      *(u16x8*)&Vout[(size_t)(j0 + row) * N + i0 + cc] = vv;
    }
  }
}

// ---------------- K3b: d = rsqrt(rowsum), in place ----------------
__global__ void dfin(float* rs) {
  int i = blockIdx.x * 256 + threadIdx.x;
  if (i < N) rs[i] = rsqrtf(rs[i]);
}

// ---------------- K4: outmm — fused scale + A_hat write + out = A_hat @ M2 (R7) ----------------
__global__ __launch_bounds__(256) void outmm(const unsigned short* __restrict__ Vin,
                      const float* __restrict__ dd,
                      const unsigned short* __restrict__ M2T,
                      float* __restrict__ Ahat, float* __restrict__ out) {
  __shared__ unsigned short la[2][128 * LDP];
  int kc = blockIdx.x;   // 0..15  (j-chunk of 512)
  int it = blockIdx.y;   // 0..63  (i-tile of 128)
  int i0 = it * 128;
  int jbase = kc * 512;
  int t = threadIdx.x;
  int w = t >> 6, l = t & 63;
  int lr = l & 15, lg = l >> 4;

  f32x4 acc[2][4];
  f32x4 zero = {0.f, 0.f, 0.f, 0.f};
  #pragma unroll
  for (int m = 0; m < 2; ++m)
    #pragma unroll
    for (int n = 0; n < 4; ++n) acc[m][n] = zero;

  const unsigned short* V = (const unsigned short*)Vin;
  const int row8 = t >> 3;      // 0..31
  const int cc8 = (t & 7) * 8;  // 0..56

  float di[4];
  #pragma unroll
  for (int rep = 0; rep < 4; ++rep) di[rep] = dd[i0 + rep * 32 + row8];

  u16x8 u[2][4];
  #pragma unroll
  for (int rep = 0; rep < 4; ++rep)
    u[0][rep] = *(const u16x8*)&V[(size_t)(i0 + rep * 32 + row8) * N + jbase + cc8];

  #pragma unroll
  for (int s = 0; s < 8; ++s) {
    const int cur = s & 1;
    const int j0 = jbase + s * 64;
    if (s < 7) {
      #pragma unroll
      for (int rep = 0; rep < 4; ++rep)
        u[cur ^ 1][rep] = *(const u16x8*)&V[(size_t)(i0 + rep * 32 + row8) * N + j0 + 64 + cc8];
    }
    short8 bfr[2][4];
    #pragma unroll
    for (int kk = 0; kk < 2; ++kk)
      #pragma unroll
      for (int n = 0; n < 4; ++n)
        bfr[kk][n] = *(const short8*)&M2T[(size_t)(n * 16 + lr) * N + j0 + kk * 32 + lg * 8];
    f32x4 dj0 = *(const f32x4*)&dd[j0 + cc8];
    f32x4 dj1 = *(const f32x4*)&dd[j0 + cc8 + 4];
    #pragma unroll
    for (int rep = 0; rep < 4; ++rep) {
      int row = rep * 32 + row8;
      size_t idx = (size_t)(i0 + row) * N + j0 + cc8;
      f32x4 s0, s1;
      s0[0] = bf2f(u[cur][rep][0]) * di[rep] * dj0[0];
      s0[1] = bf2f(u[cur][rep][1]) * di[rep] * dj0[1];
      s0[2] = bf2f(u[cur][rep][2]) * di[rep] * dj0[2];
      s0[3] = bf2f(u[cur][rep][3]) * di[rep] * dj0[3];
      s1[0] = bf2f(u[cur][rep][4]) * di[rep] * dj1[0];
      s1[1] = bf2f(u[cur][rep][5]) * di[rep] * dj1[1];
      s1[2] = bf2f(u[cur][rep][6]) * di[rep] * dj1[2];
      s1[3] = bf2f(u[cur][rep][7]) * di[rep] * dj1[3];
      *(f32x4*)&Ahat[idx] = s0;
      *(f32x4*)&Ahat[idx + 4] = s1;
      u16x8 b;
      b[0] = f2bf(s0[0]); b[1] = f2bf(s0[1]); b[2] = f2bf(s0[2]); b[3] = f2bf(s0[3]);
      b[4] = f2bf(s1[0]); b[5] = f2bf(s1[1]); b[6] = f2bf(s1[2]); b[7] = f2bf(s1[3]);
      *(u16x8*)&la[cur][row * LDP + cc8] = b;
    }
    LGKM_BAR();   // ds_writes visible; Ahat stores & prefetch loads keep flying
    #pragma unroll
    for (int kk = 0; kk < 2; ++kk) {
      short8 af[2];
      #pragma unroll
      for (int m = 0; m < 2; ++m)
        af[m] = *(const short8*)&la[cur][(w * 32 + m * 16 + lr) * LDP + kk * 32 + lg * 8];
      #pragma unroll
      for (int m = 0; m < 2; ++m)
        #pragma unroll
        for (int n = 0; n < 4; ++n)
          acc[m][n] = __builtin_amdgcn_mfma_f32_16x16x32_bf16(af[m], bfr[kk][n], acc[m][n], 0, 0, 0);
    }
  }

  #pragma unroll
  for (int m = 0; m < 2; ++m)
    #pragma unroll
    for (int n = 0; n < 4; ++n)
      #pragma unroll
      for (int r = 0; r < 4; ++r) {
        int gi = i0 + w * 32 + m * 16 + lg * 4 + r;
        int gc = n * 16 + lr;
        atomicAdd(&out[(size_t)gi * DOUT + gc], acc[m][n][r]);
      }
}

// ---------------- K5: LeakyReLU on out ----------------
__global__ void leaky(float* out) {
  int i = blockIdx.x * 256 + threadIdx.x;
  if (i < N * DOUT) {
    float x = out[i];
    out[i] = x >= 0.f ? x : 0.01f * x;
  }
}

extern "C" void kernel_launch(void* const* d_in, const int* in_sizes, int n_in,
                              void* d_out, int out_size, void* d_ws, size_t ws_size,
                              hipStream_t stream) {
  const float* H   = (const float*)d_in[0];
  const float* A   = (const float*)d_in[1];
  const float* bnw = (const float*)d_in[2];
  const float* bnb = (const float*)d_in[3];
  const float* Wt  = (const float*)d_in[4];
  const float* bt  = (const float*)d_in[5];
  const float* Wo  = (const float*)d_in[6];
  const float* bo  = (const float*)d_in[7];
  float* out = (float*)d_out;
  float* Ahat = out + (size_t)N * DOUT;

  char* ws = (char*)d_ws;
  float* scale  = (float*)(ws + 0);
  float* shift  = (float*)(ws + 512);
  float* rowsum = (float*)(ws + 4096);                    // becomes d after dfin
  unsigned short* M2T = (unsigned short*)(ws + 65536);    // 1 MB slot [64][N]
  unsigned short* Hx  = (unsigned short*)(ws + 2097152);  // 4 MB slot
  unsigned long long* Mb = (unsigned long long*)(ws + (size_t)(6u << 20));  // 8 MB bitmask
  unsigned short* Vbf = (unsigned short*)(ws + (size_t)(14u << 20));        // 128 MiB slot

  hipMemsetAsync(rowsum, 0, N * sizeof(float), stream);
  hipMemsetAsync(out, 0, (size_t)N * DOUT * sizeof(float), stream);

  maskpack<<<4096, 256, 0, stream>>>(A, Mb);
  bn_stats<<<DIN, 256, 0, stream>>>(H, bnw, bnb, scale, shift);
  proj<<<N / 8, 256, 0, stream>>>(H, scale, shift, Wt, bt, Wo, bo, Hx, M2T);
  smat<<<dim3(64, 64), 256, 0, stream>>>(Hx, Mb, rowsum, Vbf);
  dfin<<<N / 256, 256, 0, stream>>>(rowsum);
  outmm<<<dim3(16, 64), 256, 0, stream>>>(Vbf, rowsum, M2T, Ahat, out);
  leaky<<<(N * DOUT + 255) / 256, 256, 0, stream>>>(out);
}

// Round 16
// 309.992 us; speedup vs baseline: 1.2317x; 1.0257x over previous
//
#include <hip/hip_runtime.h>
#include <hip/hip_bf16.h>

#define N 8192
#define DIN 128
#define DHID 256
#define DOUT 64
#define LDP 72   // outmm staging LDS row stride (ushorts)
#define VP 136   // V-epilogue LDS row stride (ushorts)

typedef __attribute__((ext_vector_type(8))) short short8;
typedef __attribute__((ext_vector_type(8))) unsigned short u16x8;
typedef __attribute__((ext_vector_type(4))) float f32x4;
typedef __attribute__((ext_vector_type(2))) float f32x2;

typedef __attribute__((address_space(1))) const unsigned int GlbU32;
typedef __attribute__((address_space(3))) unsigned int LdsU32;

__device__ inline void gload16(const void* g, void* l) {
  __builtin_amdgcn_global_load_lds((GlbU32*)g, (LdsU32*)l, 16, 0, 0);
}

// lgkmcnt-only barrier: LDS ordering without draining vmcnt (global stores keep flying)
#define LGKM_BAR()                                            \
  do {                                                        \
    asm volatile("s_waitcnt lgkmcnt(0)" ::: "memory");        \
    __builtin_amdgcn_sched_barrier(0);                        \
    __builtin_amdgcn_s_barrier();                             \
    __builtin_amdgcn_sched_barrier(0);                        \
  } while (0)

__device__ inline unsigned short f2bf(float x) {
  unsigned u = __float_as_uint(x);
  u += 0x7FFF + ((u >> 16) & 1);   // RNE
  return (unsigned short)(u >> 16);
}
__device__ inline float bf2f(unsigned short u) {
  return __uint_as_float(((unsigned)u) << 16);
}
__device__ inline float sig_clip(float x) {
  float s = 1.0f / (1.0f + __expf(-x));
  return fmaxf(s, 0.1f);
}

// ---------------- K1: BatchNorm statistics ----------------
__global__ void bn_stats(const float* __restrict__ H, const float* __restrict__ bnw,
                         const float* __restrict__ bnb, float* __restrict__ scale,
                         float* __restrict__ shift) {
  int f = blockIdx.x;
  int t = threadIdx.x;
  float s = 0.f, sq = 0.f;
  for (int r = t; r < N; r += 256) {
    float v = H[(size_t)r * DIN + f];
    s += v; sq += v * v;
  }
  __shared__ float ss[256], s2[256];
  ss[t] = s; s2[t] = sq;
  __syncthreads();
  for (int o = 128; o > 0; o >>= 1) {
    if (t < o) { ss[t] += ss[t + o]; s2[t] += s2[t + o]; }
    __syncthreads();
  }
  if (t == 0) {
    float mean = ss[0] * (1.0f / N);
    float var = s2[0] * (1.0f / N) - mean * mean;
    float sc = rsqrtf(var + 1e-5f) * bnw[f];
    scale[f] = sc;
    shift[f] = bnb[f] - mean * sc;
  }
}

// ---------------- K2: Hn -> Hx bf16 [N,256], M2T bf16 [64][N] ----------------
__global__ __launch_bounds__(256) void proj(const float* __restrict__ H,
                     const float* __restrict__ scale, const float* __restrict__ shift,
                     const float* __restrict__ Wt, const float* __restrict__ bt,
                     const float* __restrict__ Wo, const float* __restrict__ bo,
                     unsigned short* __restrict__ Hx, unsigned short* __restrict__ M2T) {
  __shared__ float hn[8][DIN];
  int i0 = blockIdx.x * 8;
  int t = threadIdx.x;
  #pragma unroll
  for (int rep = 0; rep < 4; ++rep) {
    int idx = rep * 256 + t;
    int r = idx >> 7, c = idx & 127;
    float h = H[(size_t)(i0 + r) * DIN + c];
    hn[r][c] = fmaf(h, scale[c], shift[c]);
  }
  __syncthreads();
  {
    int c = t;
    float acc[8];
    float b = bt[c];
    #pragma unroll
    for (int r = 0; r < 8; ++r) acc[r] = b;
    for (int k = 0; k < DIN; ++k) {
      float w = Wt[k * DHID + c];
      #pragma unroll
      for (int r = 0; r < 8; ++r) acc[r] = fmaf(hn[r][k], w, acc[r]);
    }
    #pragma unroll
    for (int r = 0; r < 8; ++r) Hx[(size_t)(i0 + r) * DHID + c] = f2bf(acc[r]);
  }
  if (t < DOUT) {
    int c = t;
    float acc[8];
    float b = bo[c];
    #pragma unroll
    for (int r = 0; r < 8; ++r) acc[r] = b;
    for (int k = 0; k < DIN; ++k) {
      float w = Wo[k * DOUT + c];
      #pragma unroll
      for (int r = 0; r < 8; ++r) acc[r] = fmaf(hn[r][k], w, acc[r]);
    }
    u16x8 v;
    #pragma unroll
    for (int r = 0; r < 8; ++r) v[r] = f2bf(acc[r]);
    *(u16x8*)&M2T[(size_t)c * N + i0] = v;
  }
}

// ---------------- K3: smat — symmetric single pass, FUSED A-scan (no maskpack) ----------------
// v = clip(sig(Hx Hx^T))*mask + I, it<=jt only. Mask comes from in-loop f32x2
// A-tile loads issued concurrently with staging; ballots after the barrier.
// Bitmask layout (even/odd): row words [lo(be),hi(be),lo(bo),hi(bo)], lane l of
// ballot b_even/b_odd covers cols 2l / 2l+1.
__global__ __launch_bounds__(256) void smat(const unsigned short* __restrict__ Hx,
                     const float* __restrict__ A,
                     float* __restrict__ rowsum,
                     unsigned short* __restrict__ Vout) {
  int jt = blockIdx.x, it = blockIdx.y;
  if (jt < it) return;
  __shared__ unsigned short lsh[17408];       // staging la/lb; later the V tile [128][VP]
  __shared__ unsigned mbt32[128][4];
  __shared__ unsigned mbtT[128][4];
  __shared__ float scs[4][128];
  unsigned short* la = lsh;
  unsigned short* lb = lsh + 8192;
  int i0 = it * 128, j0 = jt * 128;
  int t = threadIdx.x;
  int w = t >> 6, l = t & 63;
  int lr = l & 15, lg = l >> 4;
  const bool offdiag = (it != jt);

  f32x4 acc[2][8];
  f32x4 zero = {0.f, 0.f, 0.f, 0.f};
  #pragma unroll
  for (int m = 0; m < 2; ++m)
    #pragma unroll
    for (int n = 0; n < 8; ++n) acc[m][n] = zero;

  const int srow = l >> 3;
  const int scol = ((l & 7) ^ srow) * 8;
  const int fswz = (lr & 7) * 8;

  for (int c4 = 0; c4 < 4; ++c4) {
    int k0 = c4 * 64;
    __syncthreads();
    #pragma unroll
    for (int rp = 0; rp < 4; ++rp) {
      int chunk = rp * 4 + w;
      int row = chunk * 8 + srow;
      gload16(&Hx[(size_t)(i0 + row) * DHID + k0 + scol], &la[chunk * 512]);
      gload16(&Hx[(size_t)(j0 + row) * DHID + k0 + scol], &lb[chunk * 512]);
    }
    // A-tile loads for this c4's 8 rows/wave (concurrent with staging; the
    // following __syncthreads drains vmcnt for both streams together)
    const int rbase = w * 32 + c4 * 8;
    f32x2 au[8], al[8];
    #pragma unroll
    for (int rr = 0; rr < 8; ++rr)
      au[rr] = *(const f32x2*)&A[(size_t)(i0 + rbase + rr) * N + j0 + 2 * l];
    if (offdiag) {
      #pragma unroll
      for (int rr = 0; rr < 8; ++rr)
        al[rr] = *(const f32x2*)&A[(size_t)(j0 + rbase + rr) * N + i0 + 2 * l];
    }
    __syncthreads();
    // ballots -> LDS bitmask (data already resident; short reg lifetime)
    #pragma unroll
    for (int rr = 0; rr < 8; ++rr) {
      unsigned long long be = __ballot(au[rr][0] > 0.f);
      unsigned long long bo = __ballot(au[rr][1] > 0.f);
      if (l == 0) {
        mbt32[rbase + rr][0] = (unsigned)be;
        mbt32[rbase + rr][1] = (unsigned)(be >> 32);
        mbt32[rbase + rr][2] = (unsigned)bo;
        mbt32[rbase + rr][3] = (unsigned)(bo >> 32);
      }
    }
    if (offdiag) {
      #pragma unroll
      for (int rr = 0; rr < 8; ++rr) {
        unsigned long long be = __ballot(al[rr][0] > 0.f);
        unsigned long long bo = __ballot(al[rr][1] > 0.f);
        if (l == 0) {
          mbtT[rbase + rr][0] = (unsigned)be;
          mbtT[rbase + rr][1] = (unsigned)(be >> 32);
          mbtT[rbase + rr][2] = (unsigned)bo;
          mbtT[rbase + rr][3] = (unsigned)(bo >> 32);
        }
      }
    }
    #pragma unroll
    for (int kk = 0; kk < 2; ++kk) {
      int c = (kk * 32 + lg * 8) ^ fswz;
      short8 af[2], bf[8];
      #pragma unroll
      for (int m = 0; m < 2; ++m)
        af[m] = *(const short8*)&la[(w * 32 + m * 16 + lr) * 64 + c];
      #pragma unroll
      for (int n = 0; n < 8; ++n)
        bf[n] = *(const short8*)&lb[(n * 16 + lr) * 64 + c];
      #pragma unroll
      for (int m = 0; m < 2; ++m)
        #pragma unroll
        for (int n = 0; n < 8; ++n)
          acc[m][n] = __builtin_amdgcn_mfma_f32_16x16x32_bf16(af[m], bf[n], acc[m][n], 0, 0, 0);
    }
  }

  LGKM_BAR();  // MFMA ds_reads + mask ds_writes retired; lsh becomes the V tile

  // ---- upper tile: s = sig_clip(acc) cached; v_up = s*m_up (+I), row sums ----
  // decode: col c = n*16+lr -> word (lr&1)*2 + (n>>2), bit (n&3)*8 + (lr>>1)
  #pragma unroll
  for (int m = 0; m < 2; ++m) {
    #pragma unroll
    for (int r = 0; r < 4; ++r) {
      int rl = w * 32 + m * 16 + lg * 4 + r;
      int gi = i0 + rl;
      unsigned w0 = mbt32[rl][(lr & 1) * 2];
      unsigned w1 = mbt32[rl][(lr & 1) * 2 + 1];
      float part = 0.f;
      #pragma unroll
      for (int n = 0; n < 8; ++n) {
        int gj = j0 + n * 16 + lr;
        float s = sig_clip(acc[m][n][r]);
        acc[m][n][r] = s;                       // cache for lower pass (no 2nd exp)
        unsigned mwv = (n < 4) ? w0 : w1;
        float ms = ((mwv >> ((n & 3) * 8 + (lr >> 1))) & 1u) ? 1.f : 0.f;
        float v = s * ms + (gi == gj ? 1.f : 0.f);
        part += v;
        lsh[rl * VP + n * 16 + lr] = f2bf(v);
      }
      part += __shfl_xor(part, 1);
      part += __shfl_xor(part, 2);
      part += __shfl_xor(part, 4);
      part += __shfl_xor(part, 8);
      if (lr == 0) atomicAdd(&rowsum[gi], part);
    }
  }

  LGKM_BAR();     // V tile visible; no vmem drain
  #pragma unroll
  for (int pass = 0; pass < 8; ++pass) {
    int row = pass * 16 + (t >> 4);
    int cc = (t & 15) * 8;
    u16x8 vv = *(const u16x8*)&lsh[row * VP + cc];
    *(u16x8*)&Vout[(size_t)(i0 + row) * N + j0 + cc] = vv;
  }

  // ---- lower (transposed) tile: v_lo = s*m_lo, column sums -> rowsum[j-rows] ----
  // decode: col rl = w*32+m*16+lg*4+r -> word (r&1)*2 + (w>>1),
  //         bit (w&1)*16 + m*8 + lg*2 + (r>>1)
  if (offdiag) {
    LGKM_BAR();   // upper store pass's LDS reads retired; stores keep flying
    float p[8];
    #pragma unroll
    for (int n = 0; n < 8; ++n) p[n] = 0.f;
    #pragma unroll
    for (int m = 0; m < 2; ++m) {
      #pragma unroll
      for (int r = 0; r < 4; ++r) {
        int rl = w * 32 + m * 16 + lg * 4 + r;
        int wi = (r & 1) * 2 + (w >> 1);
        int bitp = (w & 1) * 16 + m * 8 + lg * 2 + (r >> 1);
        #pragma unroll
        for (int n = 0; n < 8; ++n) {
          int c = n * 16 + lr;                       // j-row within tile
          float ms = ((mbtT[c][wi] >> bitp) & 1u) ? 1.f : 0.f;
          float v = acc[m][n][r] * ms;               // s already cached — no exp
          p[n] += v;
          lsh[c * VP + rl] = f2bf(v);                // transposed position
        }
      }
    }
    #pragma unroll
    for (int n = 0; n < 8; ++n) {
      p[n] += __shfl_xor(p[n], 16);
      p[n] += __shfl_xor(p[n], 32);
    }
    if (lg == 0) {
      #pragma unroll
      for (int n = 0; n < 8; ++n) scs[w][n * 16 + lr] = p[n];
    }
    LGKM_BAR();   // lsh transposed tile + scs visible
    if (t < 128) {
      float cs = scs[0][t] + scs[1][t] + scs[2][t] + scs[3][t];
      atomicAdd(&rowsum[j0 + t], cs);
    }
    #pragma unroll
    for (int pass = 0; pass < 8; ++pass) {
      int row = pass * 16 + (t >> 4);
      int cc = (t & 15) * 8;
      u16x8 vv = *(const u16x8*)&lsh[row * VP + cc];
      *(u16x8*)&Vout[(size_t)(j0 + row) * N + i0 + cc] = vv;
    }
  }
}

// ---------------- K3b: d = rsqrt(rowsum), in place ----------------
__global__ void dfin(float* rs) {
  int i = blockIdx.x * 256 + threadIdx.x;
  if (i < N) rs[i] = rsqrtf(rs[i]);
}

// ---------------- K4: outmm — fused scale + A_hat write + out = A_hat @ M2 (R7) ----------------
__global__ __launch_bounds__(256) void outmm(const unsigned short* __restrict__ Vin,
                      const float* __restrict__ dd,
                      const unsigned short* __restrict__ M2T,
                      float* __restrict__ Ahat, float* __restrict__ out) {
  __shared__ unsigned short la[2][128 * LDP];
  int kc = blockIdx.x;   // 0..15  (j-chunk of 512)
  int it = blockIdx.y;   // 0..63  (i-tile of 128)
  int i0 = it * 128;
  int jbase = kc * 512;
  int t = threadIdx.x;
  int w = t >> 6, l = t & 63;
  int lr = l & 15, lg = l >> 4;

  f32x4 acc[2][4];
  f32x4 zero = {0.f, 0.f, 0.f, 0.f};
  #pragma unroll
  for (int m = 0; m < 2; ++m)
    #pragma unroll
    for (int n = 0; n < 4; ++n) acc[m][n] = zero;

  const unsigned short* V = (const unsigned short*)Vin;
  const int row8 = t >> 3;      // 0..31
  const int cc8 = (t & 7) * 8;  // 0..56

  float di[4];
  #pragma unroll
  for (int rep = 0; rep < 4; ++rep) di[rep] = dd[i0 + rep * 32 + row8];

  u16x8 u[2][4];
  #pragma unroll
  for (int rep = 0; rep < 4; ++rep)
    u[0][rep] = *(const u16x8*)&V[(size_t)(i0 + rep * 32 + row8) * N + jbase + cc8];

  #pragma unroll
  for (int s = 0; s < 8; ++s) {
    const int cur = s & 1;
    const int j0 = jbase + s * 64;
    if (s < 7) {
      #pragma unroll
      for (int rep = 0; rep < 4; ++rep)
        u[cur ^ 1][rep] = *(const u16x8*)&V[(size_t)(i0 + rep * 32 + row8) * N + j0 + 64 + cc8];
    }
    short8 bfr[2][4];
    #pragma unroll
    for (int kk = 0; kk < 2; ++kk)
      #pragma unroll
      for (int n = 0; n < 4; ++n)
        bfr[kk][n] = *(const short8*)&M2T[(size_t)(n * 16 + lr) * N + j0 + kk * 32 + lg * 8];
    f32x4 dj0 = *(const f32x4*)&dd[j0 + cc8];
    f32x4 dj1 = *(const f32x4*)&dd[j0 + cc8 + 4];
    #pragma unroll
    for (int rep = 0; rep < 4; ++rep) {
      int row = rep * 32 + row8;
      size_t idx = (size_t)(i0 + row) * N + j0 + cc8;
      f32x4 s0, s1;
      s0[0] = bf2f(u[cur][rep][0]) * di[rep] * dj0[0];
      s0[1] = bf2f(u[cur][rep][1]) * di[rep] * dj0[1];
      s0[2] = bf2f(u[cur][rep][2]) * di[rep] * dj0[2];
      s0[3] = bf2f(u[cur][rep][3]) * di[rep] * dj0[3];
      s1[0] = bf2f(u[cur][rep][4]) * di[rep] * dj1[0];
      s1[1] = bf2f(u[cur][rep][5]) * di[rep] * dj1[1];
      s1[2] = bf2f(u[cur][rep][6]) * di[rep] * dj1[2];
      s1[3] = bf2f(u[cur][rep][7]) * di[rep] * dj1[3];
      *(f32x4*)&Ahat[idx] = s0;
      *(f32x4*)&Ahat[idx + 4] = s1;
      u16x8 b;
      b[0] = f2bf(s0[0]); b[1] = f2bf(s0[1]); b[2] = f2bf(s0[2]); b[3] = f2bf(s0[3]);
      b[4] = f2bf(s1[0]); b[5] = f2bf(s1[1]); b[6] = f2bf(s1[2]); b[7] = f2bf(s1[3]);
      *(u16x8*)&la[cur][row * LDP + cc8] = b;
    }
    LGKM_BAR();   // ds_writes visible; Ahat stores & prefetch loads keep flying
    #pragma unroll
    for (int kk = 0; kk < 2; ++kk) {
      short8 af[2];
      #pragma unroll
      for (int m = 0; m < 2; ++m)
        af[m] = *(const short8*)&la[cur][(w * 32 + m * 16 + lr) * LDP + kk * 32 + lg * 8];
      #pragma unroll
      for (int m = 0; m < 2; ++m)
        #pragma unroll
        for (int n = 0; n < 4; ++n)
          acc[m][n] = __builtin_amdgcn_mfma_f32_16x16x32_bf16(af[m], bfr[kk][n], acc[m][n], 0, 0, 0);
    }
  }

  #pragma unroll
  for (int m = 0; m < 2; ++m)
    #pragma unroll
    for (int n = 0; n < 4; ++n)
      #pragma unroll
      for (int r = 0; r < 4; ++r) {
        int gi = i0 + w * 32 + m * 16 + lg * 4 + r;
        int gc = n * 16 + lr;
        atomicAdd(&out[(size_t)gi * DOUT + gc], acc[m][n][r]);
      }
}

// ---------------- K5: LeakyReLU on out ----------------
__global__ void leaky(float* out) {
  int i = blockIdx.x * 256 + threadIdx.x;
  if (i < N * DOUT) {
    float x = out[i];
    out[i] = x >= 0.f ? x : 0.01f * x;
  }
}

extern "C" void kernel_launch(void* const* d_in, const int* in_sizes, int n_in,
                              void* d_out, int out_size, void* d_ws, size_t ws_size,
                              hipStream_t stream) {
  const float* H   = (const float*)d_in[0];
  const float* A   = (const float*)d_in[1];
  const float* bnw = (const float*)d_in[2];
  const float* bnb = (const float*)d_in[3];
  const float* Wt  = (const float*)d_in[4];
  const float* bt  = (const float*)d_in[5];
  const float* Wo  = (const float*)d_in[6];
  const float* bo  = (const float*)d_in[7];
  float* out = (float*)d_out;
  float* Ahat = out + (size_t)N * DOUT;

  char* ws = (char*)d_ws;
  float* scale  = (float*)(ws + 0);
  float* shift  = (float*)(ws + 512);
  float* rowsum = (float*)(ws + 4096);                    // becomes d after dfin
  unsigned short* M2T = (unsigned short*)(ws + 65536);    // 1 MB slot [64][N]
  unsigned short* Hx  = (unsigned short*)(ws + 2097152);  // 4 MB slot
  unsigned short* Vbf = (unsigned short*)(ws + (size_t)(14u << 20));        // 128 MiB slot

  hipMemsetAsync(rowsum, 0, N * sizeof(float), stream);
  hipMemsetAsync(out, 0, (size_t)N * DOUT * sizeof(float), stream);

  bn_stats<<<DIN, 256, 0, stream>>>(H, bnw, bnb, scale, shift);
  proj<<<N / 8, 256, 0, stream>>>(H, scale, shift, Wt, bt, Wo, bo, Hx, M2T);
  smat<<<dim3(64, 64), 256, 0, stream>>>(Hx, A, rowsum, Vbf);
  dfin<<<N / 256, 256, 0, stream>>>(rowsum);
  outmm<<<dim3(16, 64), 256, 0, stream>>>(Vbf, rowsum, M2T, Ahat, out);
  leaky<<<(N * DOUT + 255) / 256, 256, 0, stream>>>(out);
}

// Round 17
// 308.080 us; speedup vs baseline: 1.2393x; 1.0062x over previous
//
#include <hip/hip_runtime.h>
#include <hip/hip_bf16.h>

#define N 8192
#define DIN 128
#define DHID 256
#define DOUT 64
#define LDP 72   // outmm staging LDS row stride (ushorts)
#define VP 136   // V-epilogue LDS row stride (ushorts)

typedef __attribute__((ext_vector_type(8))) short short8;
typedef __attribute__((ext_vector_type(8))) unsigned short u16x8;
typedef __attribute__((ext_vector_type(4))) float f32x4;
typedef __attribute__((ext_vector_type(2))) float f32x2;

typedef __attribute__((address_space(1))) const unsigned int GlbU32;
typedef __attribute__((address_space(3))) unsigned int LdsU32;

__device__ inline void gload16(const void* g, void* l) {
  __builtin_amdgcn_global_load_lds((GlbU32*)g, (LdsU32*)l, 16, 0, 0);
}

// lgkmcnt-only barrier: LDS ordering without draining vmcnt (global stores keep flying)
#define LGKM_BAR()                                            \
  do {                                                        \
    asm volatile("s_waitcnt lgkmcnt(0)" ::: "memory");        \
    __builtin_amdgcn_sched_barrier(0);                        \
    __builtin_amdgcn_s_barrier();                             \
    __builtin_amdgcn_sched_barrier(0);                        \
  } while (0)

__device__ inline unsigned short f2bf(float x) {
  unsigned u = __float_as_uint(x);
  u += 0x7FFF + ((u >> 16) & 1);   // RNE
  return (unsigned short)(u >> 16);
}
__device__ inline float bf2f(unsigned short u) {
  return __uint_as_float(((unsigned)u) << 16);
}
__device__ inline float sig_clip(float x) {
  float s = 1.0f / (1.0f + __expf(-x));
  return fmaxf(s, 0.1f);
}

// ---------------- K1: BatchNorm statistics ----------------
__global__ void bn_stats(const float* __restrict__ H, const float* __restrict__ bnw,
                         const float* __restrict__ bnb, float* __restrict__ scale,
                         float* __restrict__ shift) {
  int f = blockIdx.x;
  int t = threadIdx.x;
  float s = 0.f, sq = 0.f;
  for (int r = t; r < N; r += 256) {
    float v = H[(size_t)r * DIN + f];
    s += v; sq += v * v;
  }
  __shared__ float ss[256], s2[256];
  ss[t] = s; s2[t] = sq;
  __syncthreads();
  for (int o = 128; o > 0; o >>= 1) {
    if (t < o) { ss[t] += ss[t + o]; s2[t] += s2[t + o]; }
    __syncthreads();
  }
  if (t == 0) {
    float mean = ss[0] * (1.0f / N);
    float var = s2[0] * (1.0f / N) - mean * mean;
    float sc = rsqrtf(var + 1e-5f) * bnw[f];
    scale[f] = sc;
    shift[f] = bnb[f] - mean * sc;
  }
}

// ---------------- K2: Hn -> Hx bf16 [N,256], M2T bf16 [64][N] ----------------
__global__ __launch_bounds__(256) void proj(const float* __restrict__ H,
                     const float* __restrict__ scale, const float* __restrict__ shift,
                     const float* __restrict__ Wt, const float* __restrict__ bt,
                     const float* __restrict__ Wo, const float* __restrict__ bo,
                     unsigned short* __restrict__ Hx, unsigned short* __restrict__ M2T) {
  __shared__ float hn[8][DIN];
  int i0 = blockIdx.x * 8;
  int t = threadIdx.x;
  #pragma unroll
  for (int rep = 0; rep < 4; ++rep) {
    int idx = rep * 256 + t;
    int r = idx >> 7, c = idx & 127;
    float h = H[(size_t)(i0 + r) * DIN + c];
    hn[r][c] = fmaf(h, scale[c], shift[c]);
  }
  __syncthreads();
  {
    int c = t;
    float acc[8];
    float b = bt[c];
    #pragma unroll
    for (int r = 0; r < 8; ++r) acc[r] = b;
    for (int k = 0; k < DIN; ++k) {
      float w = Wt[k * DHID + c];
      #pragma unroll
      for (int r = 0; r < 8; ++r) acc[r] = fmaf(hn[r][k], w, acc[r]);
    }
    #pragma unroll
    for (int r = 0; r < 8; ++r) Hx[(size_t)(i0 + r) * DHID + c] = f2bf(acc[r]);
  }
  if (t < DOUT) {
    int c = t;
    float acc[8];
    float b = bo[c];
    #pragma unroll
    for (int r = 0; r < 8; ++r) acc[r] = b;
    for (int k = 0; k < DIN; ++k) {
      float w = Wo[k * DOUT + c];
      #pragma unroll
      for (int r = 0; r < 8; ++r) acc[r] = fmaf(hn[r][k], w, acc[r]);
    }
    u16x8 v;
    #pragma unroll
    for (int r = 0; r < 8; ++r) v[r] = f2bf(acc[r]);
    *(u16x8*)&M2T[(size_t)c * N + i0] = v;
  }
}

// ---------------- K3: smat — symmetric single pass, fused A-scan, scs aliased to mbt32 ----------------
// Identical to R16 except scs (2 KB) aliases mbt32's storage (lifetimes are
// barrier-separated: all mbt32 reads are in the upper pass, scs writes are in
// the lower pass after an LGKM_BAR). LDS 40960 -> 38912 B => 4 blocks/CU.
__global__ __launch_bounds__(256) void smat(const unsigned short* __restrict__ Hx,
                     const float* __restrict__ A,
                     float* __restrict__ rowsum,
                     unsigned short* __restrict__ Vout) {
  int jt = blockIdx.x, it = blockIdx.y;
  if (jt < it) return;
  __shared__ unsigned short lsh[17408];       // staging la/lb; later the V tile [128][VP]
  __shared__ unsigned mbt32[128][4];          // upper mask; later aliased as scs[4][128]
  __shared__ unsigned mbtT[128][4];
  unsigned short* la = lsh;
  unsigned short* lb = lsh + 8192;
  float* scs = (float*)mbt32;                 // alias: safe, lifetimes barrier-separated
  int i0 = it * 128, j0 = jt * 128;
  int t = threadIdx.x;
  int w = t >> 6, l = t & 63;
  int lr = l & 15, lg = l >> 4;
  const bool offdiag = (it != jt);

  f32x4 acc[2][8];
  f32x4 zero = {0.f, 0.f, 0.f, 0.f};
  #pragma unroll
  for (int m = 0; m < 2; ++m)
    #pragma unroll
    for (int n = 0; n < 8; ++n) acc[m][n] = zero;

  const int srow = l >> 3;
  const int scol = ((l & 7) ^ srow) * 8;
  const int fswz = (lr & 7) * 8;

  for (int c4 = 0; c4 < 4; ++c4) {
    int k0 = c4 * 64;
    __syncthreads();
    #pragma unroll
    for (int rp = 0; rp < 4; ++rp) {
      int chunk = rp * 4 + w;
      int row = chunk * 8 + srow;
      gload16(&Hx[(size_t)(i0 + row) * DHID + k0 + scol], &la[chunk * 512]);
      gload16(&Hx[(size_t)(j0 + row) * DHID + k0 + scol], &lb[chunk * 512]);
    }
    // A-tile loads for this c4's 8 rows/wave (concurrent with staging; the
    // following __syncthreads drains vmcnt for both streams together)
    const int rbase = w * 32 + c4 * 8;
    f32x2 au[8], al[8];
    #pragma unroll
    for (int rr = 0; rr < 8; ++rr)
      au[rr] = *(const f32x2*)&A[(size_t)(i0 + rbase + rr) * N + j0 + 2 * l];
    if (offdiag) {
      #pragma unroll
      for (int rr = 0; rr < 8; ++rr)
        al[rr] = *(const f32x2*)&A[(size_t)(j0 + rbase + rr) * N + i0 + 2 * l];
    }
    __syncthreads();
    // ballots -> LDS bitmask (data already resident; short reg lifetime)
    #pragma unroll
    for (int rr = 0; rr < 8; ++rr) {
      unsigned long long be = __ballot(au[rr][0] > 0.f);
      unsigned long long bo = __ballot(au[rr][1] > 0.f);
      if (l == 0) {
        mbt32[rbase + rr][0] = (unsigned)be;
        mbt32[rbase + rr][1] = (unsigned)(be >> 32);
        mbt32[rbase + rr][2] = (unsigned)bo;
        mbt32[rbase + rr][3] = (unsigned)(bo >> 32);
      }
    }
    if (offdiag) {
      #pragma unroll
      for (int rr = 0; rr < 8; ++rr) {
        unsigned long long be = __ballot(al[rr][0] > 0.f);
        unsigned long long bo = __ballot(al[rr][1] > 0.f);
        if (l == 0) {
          mbtT[rbase + rr][0] = (unsigned)be;
          mbtT[rbase + rr][1] = (unsigned)(be >> 32);
          mbtT[rbase + rr][2] = (unsigned)bo;
          mbtT[rbase + rr][3] = (unsigned)(bo >> 32);
        }
      }
    }
    #pragma unroll
    for (int kk = 0; kk < 2; ++kk) {
      int c = (kk * 32 + lg * 8) ^ fswz;
      short8 af[2], bf[8];
      #pragma unroll
      for (int m = 0; m < 2; ++m)
        af[m] = *(const short8*)&la[(w * 32 + m * 16 + lr) * 64 + c];
      #pragma unroll
      for (int n = 0; n < 8; ++n)
        bf[n] = *(const short8*)&lb[(n * 16 + lr) * 64 + c];
      #pragma unroll
      for (int m = 0; m < 2; ++m)
        #pragma unroll
        for (int n = 0; n < 8; ++n)
          acc[m][n] = __builtin_amdgcn_mfma_f32_16x16x32_bf16(af[m], bf[n], acc[m][n], 0, 0, 0);
    }
  }

  LGKM_BAR();  // MFMA ds_reads + mask ds_writes retired; lsh becomes the V tile

  // ---- upper tile: s = sig_clip(acc) cached; v_up = s*m_up (+I), row sums ----
  // decode: col c = n*16+lr -> word (lr&1)*2 + (n>>2), bit (n&3)*8 + (lr>>1)
  #pragma unroll
  for (int m = 0; m < 2; ++m) {
    #pragma unroll
    for (int r = 0; r < 4; ++r) {
      int rl = w * 32 + m * 16 + lg * 4 + r;
      int gi = i0 + rl;
      unsigned w0 = mbt32[rl][(lr & 1) * 2];
      unsigned w1 = mbt32[rl][(lr & 1) * 2 + 1];
      float part = 0.f;
      #pragma unroll
      for (int n = 0; n < 8; ++n) {
        int gj = j0 + n * 16 + lr;
        float s = sig_clip(acc[m][n][r]);
        acc[m][n][r] = s;                       // cache for lower pass (no 2nd exp)
        unsigned mwv = (n < 4) ? w0 : w1;
        float ms = ((mwv >> ((n & 3) * 8 + (lr >> 1))) & 1u) ? 1.f : 0.f;
        float v = s * ms + (gi == gj ? 1.f : 0.f);
        part += v;
        lsh[rl * VP + n * 16 + lr] = f2bf(v);
      }
      part += __shfl_xor(part, 1);
      part += __shfl_xor(part, 2);
      part += __shfl_xor(part, 4);
      part += __shfl_xor(part, 8);
      if (lr == 0) atomicAdd(&rowsum[gi], part);
    }
  }

  LGKM_BAR();     // V tile visible; no vmem drain; mbt32 reads all retired
  #pragma unroll
  for (int pass = 0; pass < 8; ++pass) {
    int row = pass * 16 + (t >> 4);
    int cc = (t & 15) * 8;
    u16x8 vv = *(const u16x8*)&lsh[row * VP + cc];
    *(u16x8*)&Vout[(size_t)(i0 + row) * N + j0 + cc] = vv;
  }

  // ---- lower (transposed) tile: v_lo = s*m_lo, column sums -> rowsum[j-rows] ----
  // decode: col rl = w*32+m*16+lg*4+r -> word (r&1)*2 + (w>>1),
  //         bit (w&1)*16 + m*8 + lg*2 + (r>>1)
  if (offdiag) {
    LGKM_BAR();   // upper store pass's LDS reads retired; stores keep flying
    float p[8];
    #pragma unroll
    for (int n = 0; n < 8; ++n) p[n] = 0.f;
    #pragma unroll
    for (int m = 0; m < 2; ++m) {
      #pragma unroll
      for (int r = 0; r < 4; ++r) {
        int rl = w * 32 + m * 16 + lg * 4 + r;
        int wi = (r & 1) * 2 + (w >> 1);
        int bitp = (w & 1) * 16 + m * 8 + lg * 2 + (r >> 1);
        #pragma unroll
        for (int n = 0; n < 8; ++n) {
          int c = n * 16 + lr;                       // j-row within tile
          float ms = ((mbtT[c][wi] >> bitp) & 1u) ? 1.f : 0.f;
          float v = acc[m][n][r] * ms;               // s already cached — no exp
          p[n] += v;
          lsh[c * VP + rl] = f2bf(v);                // transposed position
        }
      }
    }
    #pragma unroll
    for (int n = 0; n < 8; ++n) {
      p[n] += __shfl_xor(p[n], 16);
      p[n] += __shfl_xor(p[n], 32);
    }
    if (lg == 0) {
      #pragma unroll
      for (int n = 0; n < 8; ++n) scs[w * 128 + n * 16 + lr] = p[n];  // aliased mbt32
    }
    LGKM_BAR();   // lsh transposed tile + scs visible
    if (t < 128) {
      float cs = scs[0 * 128 + t] + scs[1 * 128 + t] + scs[2 * 128 + t] + scs[3 * 128 + t];
      atomicAdd(&rowsum[j0 + t], cs);
    }
    #pragma unroll
    for (int pass = 0; pass < 8; ++pass) {
      int row = pass * 16 + (t >> 4);
      int cc = (t & 15) * 8;
      u16x8 vv = *(const u16x8*)&lsh[row * VP + cc];
      *(u16x8*)&Vout[(size_t)(j0 + row) * N + i0 + cc] = vv;
    }
  }
}

// ---------------- K3b: d = rsqrt(rowsum), in place ----------------
__global__ void dfin(float* rs) {
  int i = blockIdx.x * 256 + threadIdx.x;
  if (i < N) rs[i] = rsqrtf(rs[i]);
}

// ---------------- K4: outmm — fused scale + A_hat write + out = A_hat @ M2 (R7) ----------------
__global__ __launch_bounds__(256) void outmm(const unsigned short* __restrict__ Vin,
                      const float* __restrict__ dd,
                      const unsigned short* __restrict__ M2T,
                      float* __restrict__ Ahat, float* __restrict__ out) {
  __shared__ unsigned short la[2][128 * LDP];
  int kc = blockIdx.x;   // 0..15  (j-chunk of 512)
  int it = blockIdx.y;   // 0..63  (i-tile of 128)
  int i0 = it * 128;
  int jbase = kc * 512;
  int t = threadIdx.x;
  int w = t >> 6, l = t & 63;
  int lr = l & 15, lg = l >> 4;

  f32x4 acc[2][4];
  f32x4 zero = {0.f, 0.f, 0.f, 0.f};
  #pragma unroll
  for (int m = 0; m < 2; ++m)
    #pragma unroll
    for (int n = 0; n < 4; ++n) acc[m][n] = zero;

  const unsigned short* V = (const unsigned short*)Vin;
  const int row8 = t >> 3;      // 0..31
  const int cc8 = (t & 7) * 8;  // 0..56

  float di[4];
  #pragma unroll
  for (int rep = 0; rep < 4; ++rep) di[rep] = dd[i0 + rep * 32 + row8];

  u16x8 u[2][4];
  #pragma unroll
  for (int rep = 0; rep < 4; ++rep)
    u[0][rep] = *(const u16x8*)&V[(size_t)(i0 + rep * 32 + row8) * N + jbase + cc8];

  #pragma unroll
  for (int s = 0; s < 8; ++s) {
    const int cur = s & 1;
    const int j0 = jbase + s * 64;
    if (s < 7) {
      #pragma unroll
      for (int rep = 0; rep < 4; ++rep)
        u[cur ^ 1][rep] = *(const u16x8*)&V[(size_t)(i0 + rep * 32 + row8) * N + j0 + 64 + cc8];
    }
    short8 bfr[2][4];
    #pragma unroll
    for (int kk = 0; kk < 2; ++kk)
      #pragma unroll
      for (int n = 0; n < 4; ++n)
        bfr[kk][n] = *(const short8*)&M2T[(size_t)(n * 16 + lr) * N + j0 + kk * 32 + lg * 8];
    f32x4 dj0 = *(const f32x4*)&dd[j0 + cc8];
    f32x4 dj1 = *(const f32x4*)&dd[j0 + cc8 + 4];
    #pragma unroll
    for (int rep = 0; rep < 4; ++rep) {
      int row = rep * 32 + row8;
      size_t idx = (size_t)(i0 + row) * N + j0 + cc8;
      f32x4 s0, s1;
      s0[0] = bf2f(u[cur][rep][0]) * di[rep] * dj0[0];
      s0[1] = bf2f(u[cur][rep][1]) * di[rep] * dj0[1];
      s0[2] = bf2f(u[cur][rep][2]) * di[rep] * dj0[2];
      s0[3] = bf2f(u[cur][rep][3]) * di[rep] * dj0[3];
      s1[0] = bf2f(u[cur][rep][4]) * di[rep] * dj1[0];
      s1[1] = bf2f(u[cur][rep][5]) * di[rep] * dj1[1];
      s1[2] = bf2f(u[cur][rep][6]) * di[rep] * dj1[2];
      s1[3] = bf2f(u[cur][rep][7]) * di[rep] * dj1[3];
      *(f32x4*)&Ahat[idx] = s0;
      *(f32x4*)&Ahat[idx + 4] = s1;
      u16x8 b;
      b[0] = f2bf(s0[0]); b[1] = f2bf(s0[1]); b[2] = f2bf(s0[2]); b[3] = f2bf(s0[3]);
      b[4] = f2bf(s1[0]); b[5] = f2bf(s1[1]); b[6] = f2bf(s1[2]); b[7] = f2bf(s1[3]);
      *(u16x8*)&la[cur][row * LDP + cc8] = b;
    }
    LGKM_BAR();   // ds_writes visible; Ahat stores & prefetch loads keep flying
    #pragma unroll
    for (int kk = 0; kk < 2; ++kk) {
      short8 af[2];
      #pragma unroll
      for (int m = 0; m < 2; ++m)
        af[m] = *(const short8*)&la[cur][(w * 32 + m * 16 + lr) * LDP + kk * 32 + lg * 8];
      #pragma unroll
      for (int m = 0; m < 2; ++m)
        #pragma unroll
        for (int n = 0; n < 4; ++n)
          acc[m][n] = __builtin_amdgcn_mfma_f32_16x16x32_bf16(af[m], bfr[kk][n], acc[m][n], 0, 0, 0);
    }
  }

  #pragma unroll
  for (int m = 0; m < 2; ++m)
    #pragma unroll
    for (int n = 0; n < 4; ++n)
      #pragma unroll
      for (int r = 0; r < 4; ++r) {
        int gi = i0 + w * 32 + m * 16 + lg * 4 + r;
        int gc = n * 16 + lr;
        atomicAdd(&out[(size_t)gi * DOUT + gc], acc[m][n][r]);
      }
}

// ---------------- K5: LeakyReLU on out ----------------
__global__ void leaky(float* out) {
  int i = blockIdx.x * 256 + threadIdx.x;
  if (i < N * DOUT) {
    float x = out[i];
    out[i] = x >= 0.f ? x : 0.01f * x;
  }
}

extern "C" void kernel_launch(void* const* d_in, const int* in_sizes, int n_in,
                              void* d_out, int out_size, void* d_ws, size_t ws_size,
                              hipStream_t stream) {
  const float* H   = (const float*)d_in[0];
  const float* A   = (const float*)d_in[1];
  const float* bnw = (const float*)d_in[2];
  const float* bnb = (const float*)d_in[3];
  const float* Wt  = (const float*)d_in[4];
  const float* bt  = (const float*)d_in[5];
  const float* Wo  = (const float*)d_in[6];
  const float* bo  = (const float*)d_in[7];
  float* out = (float*)d_out;
  float* Ahat = out + (size_t)N * DOUT;

  char* ws = (char*)d_ws;
  float* scale  = (float*)(ws + 0);
  float* shift  = (float*)(ws + 512);
  float* rowsum = (float*)(ws + 4096);                    // becomes d after dfin
  unsigned short* M2T = (unsigned short*)(ws + 65536);    // 1 MB slot [64][N]
  unsigned short* Hx  = (unsigned short*)(ws + 2097152);  // 4 MB slot
  unsigned short* Vbf = (unsigned short*)(ws + (size_t)(14u << 20));        // 128 MiB slot

  hipMemsetAsync(rowsum, 0, N * sizeof(float), stream);
  hipMemsetAsync(out, 0, (size_t)N * DOUT * sizeof(float), stream);

  bn_stats<<<DIN, 256, 0, stream>>>(H, bnw, bnb, scale, shift);
  proj<<<N / 8, 256, 0, stream>>>(H, scale, shift, Wt, bt, Wo, bo, Hx, M2T);
  smat<<<dim3(64, 64), 256, 0, stream>>>(Hx, A, rowsum, Vbf);
  dfin<<<N / 256, 256, 0, stream>>>(rowsum);
  outmm<<<dim3(16, 64), 256, 0, stream>>>(Vbf, rowsum, M2T, Ahat, out);
  leaky<<<(N * DOUT + 255) / 256, 256, 0, stream>>>(out);
}